// Round 1
// 1769.415 us; speedup vs baseline: 1.6718x; 1.6718x over previous
//
#include <hip/hip_runtime.h>
#include <hip/hip_bf16.h>

// RecallModel: B=16, L=2048, H=64, NH=2, HD=32, M=8, V=64.
// Inputs: ints int32; floats FP32. OUTPUTS FLOAT32 (reference dtype!):
//   out_f[0] = loss, out_f[1..1+16*2048*2048) = attn_w (B,L,L). 268,435,460 B.
//
// d_ws usage: 918,020 bytes:
//   qk15 @0       524,288 B  bf16 [Qs|K] batch 15 (layer 2)
//   imp  @524288  131,072 B  f32 imp[16][2048]
//   l2   @655360  262,144 B  f32 sum-of-exp
//   topk @917504      512 B
//   loss @918016        4 B  f32
// d_out doubles as scratch (dead-before-overwrite). attn batch-b region =
// bytes [4 + b*16777216, 4 + (b+1)*16777216).
//   h      @ byte 64         4 MB bf16 (region 0; dies at k_loss, before pass2)
//   qk1    @ byte 4194368    8 MB bf16 layer-1 [Qs|K] rows s128 (dies at attn1)
//   vg1    @ byte 12582976   4 MB bf16 layer-1 V, j-tiled (dies at attn1;
//                                 60 B spill into region 1 is dead too)
//   vg2    @ byte 4194368    4 MB bf16 layer-2 V, j-tiled (dies at attn2)
//   qk0-14 @ byte 251658304  7.7 MB (region 15; dies at pass2 wave2)
// pass2 wave1 (bz 0..14) writes regions 0..14 (reads park in region 15);
// wave2 (bz 15) reads d_ws, overwrites region 15. Loss stored LAST to out_f[0].
//
// V j-tiled layout (per batch): element (j,d) at
//   ((( (j>>5)*4 + ((j>>2)&3) )*64 + d)*8 + ((j>>4)&1)*4 + (j&3)
// so the PV B-fragment (lane g: j in {J0+4g..+3} u {J0+16+4g..+3}) is ONE
// contiguous 16 B load per lane (coalesced 256 B per 16-lane group).

typedef unsigned short u16;
#define LQ 2048
#define BBATCH 16
#define QKB 262144   // u16 elements per batch of packed [Qs|K] (2048*128)

typedef __attribute__((ext_vector_type(8))) short bf16x8;
typedef __attribute__((ext_vector_type(4))) float f32x4;

__device__ __forceinline__ float bfu2f(u16 x){ return __uint_as_float(((unsigned)x) << 16); }
__device__ __forceinline__ u16 f2bu(float f){ return __bfloat16_as_ushort(__float2bfloat16(f)); }

__device__ __forceinline__ const u16* qk_rowp(const u16* qk_r15, const u16* qk_ws,
                                              int bz, int row){
  const u16* base = (bz < 15) ? (qk_r15 + (size_t)bz*QKB) : qk_ws;
  return base + (size_t)row*128;
}
__device__ __forceinline__ u16* qk_rowp_w(u16* qk_r15, u16* qk_ws, int bz, int row){
  u16* base = (bz < 15) ? (qk_r15 + (size_t)bz*QKB) : qk_ws;
  return base + (size_t)row*128;
}

// load 8 consecutive bf16 (16 B) -> 8 fp32 (internal buffers only)
__device__ __forceinline__ void ld8bf(const u16* p, float o[8]){
  uint4 r = *(const uint4*)p;
  unsigned v[4] = {r.x, r.y, r.z, r.w};
  #pragma unroll
  for (int i=0;i<4;i++){
    o[2*i]   = __uint_as_float((v[i] & 0xffffu) << 16);
    o[2*i+1] = __uint_as_float(v[i] & 0xffff0000u);
  }
}

// ---------------- embed ----------------
__global__ __launch_bounds__(256) void k_embed(const int* __restrict__ seq,
                                               const float* __restrict__ emb,
                                               u16* __restrict__ h){
  int i = blockIdx.x*256 + threadIdx.x;      // 32768*64
  int tok = i >> 6, d = i & 63;
  int v = seq[tok] & 63;
  h[i] = f2bu(emb[(v << 6) + d]);
}

__global__ __launch_bounds__(256) void k_zero(float* __restrict__ p){
  p[blockIdx.x*256 + threadIdx.x] = 0.f;
}

// ---------------- qkv projection ----------------
// Writes [Qs|K] rows (stride 128 u16) + V in j-tiled layout (see header).
template<int MODE>
__global__ __launch_bounds__(256) void k_qkv(const u16* __restrict__ X,
                                             const float* __restrict__ W,
                                             const float* __restrict__ bias,
                                             u16* __restrict__ dqk0,
                                             u16* __restrict__ dqk_r15,
                                             u16* __restrict__ dqk_ws,
                                             u16* __restrict__ vg){
  __shared__ float WT[64*193];   // [k][mo]
  __shared__ float bs[192];
  const int t = threadIdx.x;
  for (int e=t; e<192*64; e+=256){ int mo=e>>6, k=e&63; WT[k*193+mo] = W[e]; }
  if (t < 192) bs[t] = bias[t];
  __syncthreads();
  const int wid=t>>6, lane=t&63;
  const int tok0 = (blockIdx.x*4 + wid)*4;
  float x[4];
  #pragma unroll
  for (int c=0;c<4;c++) x[c] = bfu2f(X[(tok0+c)*64 + lane]);
  float acc[4][3];
  #pragma unroll
  for (int c=0;c<4;c++)
    #pragma unroll
    for (int m=0;m<3;m++) acc[c][m] = bs[m*64 + lane];
  for (int k=0;k<64;k++){
    float wv[3];
    #pragma unroll
    for (int m=0;m<3;m++) wv[m] = WT[k*193 + m*64 + lane];
    #pragma unroll
    for (int c=0;c<4;c++){
      float xk = __shfl(x[c], k);
      #pragma unroll
      for (int m=0;m<3;m++) acc[c][m] += xk*wv[m];
    }
  }
  const float qs = 0.17677669529663688f;  // 1/sqrt(32)
  #pragma unroll
  for (int c=0;c<4;c++){
    int tok = tok0+c;
    float vq = acc[c][0]*qs, vk = acc[c][1], vv = acc[c][2];
    int b = tok >> 11, r = tok & 2047;
    u16* row = (MODE==0) ? (dqk0 + (size_t)tok*128) : qk_rowp_w(dqk_r15, dqk_ws, b, r);
    row[lane]      = f2bu(vq);
    row[64 + lane] = f2bu(vk);
    vg[((size_t)((b*64 + (r>>5))*4 + ((r>>2)&3))*64 + lane)*8
       + ((r>>4)&1)*4 + (r&3)] = f2bu(vv);
  }
}

// ---------------- score/exp helper (used by k_imp / k_pass2) ----------------
__device__ __forceinline__ void score_exp_tile(const float* Qb, const float* Kb,
                                               int qi4, int ji4, float e[4][4]){
  float a[4][4];
  #pragma unroll
  for (int qq=0;qq<4;qq++)
    #pragma unroll
    for (int jj=0;jj<4;jj++) a[qq][jj] = 0.f;
  for (int d=0; d<32; d++){
    float4 qv4 = *(const float4*)(Qb + d*64 + qi4*4);
    float4 kv4 = *(const float4*)(Kb + d*64 + ji4*4);
    float qv[4] = {qv4.x,qv4.y,qv4.z,qv4.w};
    float kv[4] = {kv4.x,kv4.y,kv4.z,kv4.w};
    #pragma unroll
    for (int qq=0;qq<4;qq++)
      #pragma unroll
      for (int jj=0;jj<4;jj++) a[qq][jj] += qv[qq]*kv[jj];
  }
  #pragma unroll
  for (int qq=0;qq<4;qq++)
    #pragma unroll
    for (int jj=0;jj<4;jj++) e[qq][jj] = __expf(a[qq][jj]);
}

// ---------------- attention (MFMA) + fused proj+residual+LN ----------------
// One block = 64 q-rows, one wave = 16 q-rows. Per k-tile (64 keys), per head:
//   S^T tiles:  D = mfma(K_frag, Q_frag)  -> lane holds S^T[j][q], q = wv*16+n
//   exp in f32, denominator accumulates in-register
//   P (bf16) is re-packed IN-LANE as the PV A-fragment (k-slot map
//   j = 16*(2kb+s/4)+4g+s%4, identical on the V B-fragment side -> exact).
// No LDS, no barriers in the main loop. K frags from [Qs|K] rows (L1-shared),
// V frags from j-tiled global (coalesced 16 B/lane).
template<int MODE>
__global__ __launch_bounds__(256) void k_attn_ln(const u16* __restrict__ PQK,
    const u16* __restrict__ QKWS, const u16* __restrict__ VG,
    const float* __restrict__ wo, const float* __restrict__ bo,
    const float* __restrict__ g, const float* __restrict__ be,
    u16* __restrict__ h, float* __restrict__ lout){
  __shared__ float sm[8768];         // 35072 B
  float* ST  = sm;                   // [64][68] attn output (f32, padded)
  float* WOT = sm + 4352;            // [64][64] wo^T
  float* CB  = sm + 8448;            // 192: bo | g | be
  float* LAC = sm + 8640;            // 128: per-head softmax denominators
  const int t = threadIdx.x;
  const int qt = blockIdx.x, bz = blockIdx.y;
  const int lane = t & 63, wv = t >> 6;
  const int n = lane & 15, gq = lane >> 4;
  const f32x4 FZ = {0.f, 0.f, 0.f, 0.f};

  // Q fragments: row q = qt*64 + wv*16 + n, d-slots = hh*32 + gq*8 .. +8
  bf16x8 qf[2];
  {
    const u16* qrow = (MODE==0) ? (PQK + (size_t)(bz*LQ + qt*64 + wv*16 + n)*128)
                                : qk_rowp(PQK, QKWS, bz, qt*64 + wv*16 + n);
    qf[0] = *(const bf16x8*)(qrow + gq*8);
    qf[1] = *(const bf16x8*)(qrow + 32 + gq*8);
  }
  f32x4 o[2][2];
  #pragma unroll
  for (int hh=0; hh<2; hh++)
    #pragma unroll
    for (int db=0; db<2; db++) o[hh][db] = FZ;
  float dacc[2] = {0.f, 0.f};

  for (int kt=0; kt<32; kt++){
    #pragma unroll
    for (int hh=0; hh<2; hh++){
      // S^T: lane (gq,n) gets S^T[j = kt*64+jb*16+4gq+reg][q = wv*16+n]
      f32x4 ev[4];
      #pragma unroll
      for (int jb=0; jb<4; jb++){
        const u16* kr = (MODE==0) ? (PQK + (size_t)(bz*LQ + kt*64 + jb*16 + n)*128)
                                  : qk_rowp(PQK, QKWS, bz, kt*64 + jb*16 + n);
        bf16x8 kf = *(const bf16x8*)(kr + 64 + hh*32 + gq*8);
        ev[jb] = __builtin_amdgcn_mfma_f32_16x16x32_bf16(kf, qf[hh], FZ, 0, 0, 0);
      }
      unsigned pk[4][2];
      float ds = 0.f;
      #pragma unroll
      for (int jb=0; jb<4; jb++){
        float e0 = __expf(ev[jb][0]), e1 = __expf(ev[jb][1]);
        float e2 = __expf(ev[jb][2]), e3 = __expf(ev[jb][3]);
        ds += (e0+e1) + (e2+e3);
        pk[jb][0] = (unsigned)f2bu(e0) | ((unsigned)f2bu(e1) << 16);
        pk[jb][1] = (unsigned)f2bu(e2) | ((unsigned)f2bu(e3) << 16);
      }
      dacc[hh] += ds;
      #pragma unroll
      for (int kb=0; kb<2; kb++){
        union { unsigned u[4]; bf16x8 v; } af;    // PV A-frag from own E's
        af.u[0] = pk[2*kb][0];   af.u[1] = pk[2*kb][1];
        af.u[2] = pk[2*kb+1][0]; af.u[3] = pk[2*kb+1][1];
        #pragma unroll
        for (int db=0; db<2; db++){
          const int d = hh*32 + db*16 + n;
          const bf16x8 vf = *(const bf16x8*)(VG +
              ((size_t)((bz*64 + kt*2 + kb)*4 + gq)*64 + d)*8);
          o[hh][db] = __builtin_amdgcn_mfma_f32_16x16x32_bf16(af.v, vf, o[hh][db], 0, 0, 0);
        }
      }
    }
  }
  // softmax denominators: reduce partial sums across the 4 gq groups
  #pragma unroll
  for (int hh=0; hh<2; hh++){
    float s = dacc[hh];
    s += __shfl_xor(s, 16);
    s += __shfl_xor(s, 32);
    if (gq == 0){
      LAC[hh*64 + wv*16 + n] = s;
      if (lout) lout[(size_t)(bz*2 + hh)*LQ + qt*64 + wv*16 + n] = s;
    }
  }
  __syncthreads();
  // normalize O -> ST[q][d] (stride 68); lane holds O[q=wv*16+4gq+r][d=hh*32+db*16+n]
  #pragma unroll
  for (int hh=0; hh<2; hh++){
    #pragma unroll
    for (int r=0; r<4; r++){
      const int q = wv*16 + gq*4 + r;
      float il = 1.f / LAC[hh*64 + q];
      ST[q*68 + hh*32 + n]      = o[hh][0][r] * il;
      ST[q*68 + hh*32 + 16 + n] = o[hh][1][r] * il;
    }
  }
  for (int e2=t; e2<4096; e2+=256){ int k=e2>>6, mo=e2&63; WOT[e2] = wo[mo*64+k]; }
  if (t < 64)       CB[t] = bo[t];
  else if (t < 128) CB[t] = g[t-64];
  else if (t < 192) CB[t] = be[t-128];
  __syncthreads();
  // proj + residual + LN
  for (int r=0; r<16; r++){
    int tl = wv*16 + r;
    size_t gtok = (size_t)(bz*LQ + qt*64 + tl);
    float acc = CB[lane];
    for (int k=0; k<64; k++) acc += ST[tl*68 + k] * WOT[k*64 + lane];
    float rr = acc + bfu2f(h[gtok*64 + lane]);
    float s = rr;
    #pragma unroll
    for (int ofs=32; ofs; ofs>>=1) s += __shfl_xor(s, ofs);
    float mean = s * (1.f/64.f);
    float dv = rr - mean;
    float vs = dv*dv;
    #pragma unroll
    for (int ofs=32; ofs; ofs>>=1) vs += __shfl_xor(vs, ofs);
    float rstd = 1.f/sqrtf(vs*(1.f/64.f) + 1e-5f);
    h[gtok*64 + lane] = f2bu(dv*rstd*CB[64+lane] + CB[128+lane]);
  }
}

// ---------------- fused FFN + residual + LN ----------------
__global__ __launch_bounds__(256) void k_ffn(u16* __restrict__ h,
    const float* __restrict__ w1, const float* __restrict__ b1,
    const float* __restrict__ w2, const float* __restrict__ b2,
    const float* __restrict__ g, const float* __restrict__ be){
  __shared__ u16 W1u[64*128];
  __shared__ u16 W2u[128*64];
  __shared__ float B1[128], B2[64], G[64], Bb[64];
  const int t = threadIdx.x;
  for (int e=t; e<8192; e+=256){ int k=e>>7, mo=e&127; W1u[e] = f2bu(w1[mo*64+k]); }
  for (int e=t; e<8192; e+=256){ int k=e>>6, mo=e&63;  W2u[e] = f2bu(w2[mo*128+k]); }
  if (t < 128) B1[t] = b1[t];
  if (t < 64){ B2[t] = b2[t]; G[t] = g[t]; Bb[t] = be[t]; }
  __syncthreads();
  const int wid = t >> 6, lane = t & 63;
  const int tok0 = (blockIdx.x*4 + wid)*4;
  float x[4];
  #pragma unroll
  for (int c=0;c<4;c++) x[c] = bfu2f(h[(tok0+c)*64 + lane]);
  #pragma unroll
  for (int c=0;c<4;c++){
    float a = B1[lane], b = B1[64+lane];
    for (int k=0;k<64;k++){
      float xk = __shfl(x[c], k);
      a += xk * bfu2f(W1u[k*128 + lane]);
      b += xk * bfu2f(W1u[k*128 + 64 + lane]);
    }
    a = fmaxf(a, 0.f); b = fmaxf(b, 0.f);
    float acc = B2[lane];
    for (int k=0;k<64;k++) acc += __shfl(a,k) * bfu2f(W2u[k*64 + lane]);
    for (int k=0;k<64;k++) acc += __shfl(b,k) * bfu2f(W2u[(64+k)*64 + lane]);
    float rr = acc + x[c];
    float s = rr;
    #pragma unroll
    for (int o=32;o;o>>=1) s += __shfl_xor(s,o);
    float mean = s * (1.f/64.f);
    float dv = rr - mean;
    float vs = dv*dv;
    #pragma unroll
    for (int o=32;o;o>>=1) vs += __shfl_xor(vs,o);
    float rstd = 1.f/sqrtf(vs*(1.f/64.f) + 1e-5f);
    h[(tok0+c)*64 + lane] = f2bu(dv*rstd*G[lane] + Bb[lane]);
  }
}

// ---------------- importance: recompute scores, atomic-accumulate ----------------
__global__ __launch_bounds__(256) void k_imp(const u16* __restrict__ qk_r15,
    const u16* __restrict__ qk_ws, const float* __restrict__ l2,
    float* __restrict__ imp){
  __shared__ float sm[8320];
  float* QT   = sm;                 // 4096 [h][d][q]
  float* KT   = sm + 4096;          // 2048
  float* IMPS = sm + 6144;          // 2048
  float* INVL = sm + 8192;          // 128
  const int t = threadIdx.x;
  const int qt = blockIdx.x, bz = blockIdx.y;
  const int j = t & 63, grp = t >> 6;
  #pragma unroll
  for (int hh=0; hh<2; hh++){
    float tmp[8];
    ld8bf(qk_rowp(qk_r15, qk_ws, bz, qt*64 + j) + hh*32 + grp*8, tmp);
    #pragma unroll
    for (int i=0;i<8;i++) QT[hh*2048 + (grp*8+i)*64 + j] = tmp[i];
  }
  if (t < 128) INVL[t] = 1.f / l2[(size_t)(bz*2 + (t>>6))*LQ + qt*64 + (t&63)];
  for (int e=t; e<2048; e+=256) IMPS[e] = 0.f;
  const int qi4 = t >> 4, ji4 = t & 15;
  float e0[4][4], e1[4][4];
  for (int kt=0; kt<32; kt++){
    __syncthreads();
    {
      float tmp[8];
      ld8bf(qk_rowp(qk_r15, qk_ws, bz, kt*64 + j) + 64 + grp*8, tmp);
      #pragma unroll
      for (int i=0;i<8;i++) KT[(grp*8+i)*64 + j] = tmp[i];
    }
    __syncthreads();
    score_exp_tile(QT, KT, qi4, ji4, e0);
    __syncthreads();
    {
      float tmp[8];
      ld8bf(qk_rowp(qk_r15, qk_ws, bz, kt*64 + j) + 96 + grp*8, tmp);
      #pragma unroll
      for (int i=0;i<8;i++) KT[(grp*8+i)*64 + j] = tmp[i];
    }
    __syncthreads();
    score_exp_tile(QT + 2048, KT, qi4, ji4, e1);
    #pragma unroll
    for (int jj=0;jj<4;jj++){
      float s = 0.f;
      #pragma unroll
      for (int qq=0;qq<4;qq++)
        s += 0.5f*(e0[qq][jj]*INVL[qi4*4+qq] + e1[qq][jj]*INVL[64+qi4*4+qq]);
      atomicAdd(&IMPS[kt*64 + ji4*4 + jj], s);
    }
  }
  __syncthreads();
  for (int e=t; e<2048; e+=256) atomicAdd(&imp[bz*LQ + e], IMPS[e]);
}

// ---------------- pass2: recompute scores, write attn_w as FLOAT32 ----------------
__global__ __launch_bounds__(256) void k_pass2(const u16* __restrict__ qk_r15,
    const u16* __restrict__ qk_ws, const float* __restrict__ l2,
    float* __restrict__ wout, int bz0){
  __shared__ float sm[10624];       // 42496 B
  float* QT   = sm;                 // 4096 [h][d][q]
  float* KT   = sm + 4096;          // 2048
  float* INVL = sm + 6144;          // 128
  float* STG  = sm + 6272;          // 4352 = [64][68] f32 staging
  const int t = threadIdx.x;
  const int qt = blockIdx.x, bz = bz0 + blockIdx.y;
  const int j = t & 63, grp = t >> 6;
  #pragma unroll
  for (int hh=0; hh<2; hh++){
    float tmp[8];
    ld8bf(qk_rowp(qk_r15, qk_ws, bz, qt*64 + j) + hh*32 + grp*8, tmp);
    #pragma unroll
    for (int i=0;i<8;i++) QT[hh*2048 + (grp*8+i)*64 + j] = tmp[i];
  }
  if (t < 128) INVL[t] = 1.f / l2[(size_t)(bz*2 + (t>>6))*LQ + qt*64 + (t&63)];
  const int qi4 = t >> 4, ji4 = t & 15;
  const int wid = t >> 6;
  float e0[4][4], e1[4][4];
  for (int kt=0; kt<32; kt++){
    __syncthreads();
    {
      float tmp[8];
      ld8bf(qk_rowp(qk_r15, qk_ws, bz, kt*64 + j) + 64 + grp*8, tmp);
      #pragma unroll
      for (int i=0;i<8;i++) KT[(grp*8+i)*64 + j] = tmp[i];
    }
    __syncthreads();
    score_exp_tile(QT, KT, qi4, ji4, e0);
    __syncthreads();
    {
      float tmp[8];
      ld8bf(qk_rowp(qk_r15, qk_ws, bz, kt*64 + j) + 96 + grp*8, tmp);
      #pragma unroll
      for (int i=0;i<8;i++) KT[(grp*8+i)*64 + j] = tmp[i];
    }
    __syncthreads();
    score_exp_tile(QT + 2048, KT, qi4, ji4, e1);
    #pragma unroll
    for (int qq=0;qq<4;qq++){
      float iv0 = INVL[qi4*4+qq], iv1 = INVL[64 + qi4*4+qq];
      *(float4*)(STG + (qi4*4+qq)*68 + ji4*4) = make_float4(
        0.5f*(e0[qq][0]*iv0 + e1[qq][0]*iv1),
        0.5f*(e0[qq][1]*iv0 + e1[qq][1]*iv1),
        0.5f*(e0[qq][2]*iv0 + e1[qq][2]*iv1),
        0.5f*(e0[qq][3]*iv0 + e1[qq][3]*iv1));
    }
    __syncthreads();
    {
      size_t base = 1 + (size_t)bz*LQ*LQ + (size_t)(qt*64)*LQ + (size_t)kt*64;
      for (int r=0;r<16;r++){
        int q = wid*16 + r;
        wout[base + (size_t)q*LQ + j] = STG[q*68 + j];
      }
    }
  }
}

// ---------------- top-k (M=8, ties -> lowest index) — LDS serial ----------------
__global__ __launch_bounds__(64) void k_topk(const float* __restrict__ imp,
                                             int* __restrict__ topki){
  __shared__ float v[2048];
  __shared__ float bv[64];
  __shared__ int   bi[64];
  __shared__ int   chosen;
  const int b = blockIdx.x, lane = threadIdx.x;
  for (int i=lane; i<2048; i+=64) v[i] = imp[b*2048 + i];
  __syncthreads();
  for (int m=0; m<8; m++){
    float best = -1e30f; int besti = 1<<30;
    for (int i=lane; i<2048; i+=64)
      if (v[i] > best || (v[i] == best && i < besti)){ best = v[i]; besti = i; }
    bv[lane] = best; bi[lane] = besti;
    __syncthreads();
    if (lane == 0){
      float B = bv[0]; int I = bi[0];
      for (int i2=1; i2<64; i2++)
        if (bv[i2] > B || (bv[i2] == B && bi[i2] < I)){ B = bv[i2]; I = bi[i2]; }
      topki[b*8 + m] = (I < 0) ? 0 : (I > 2047 ? 2047 : I);
      chosen = (I < 0) ? 0 : (I > 2047 ? 2047 : I);
    }
    __syncthreads();
    if (lane == 0) v[chosen] = -1e30f;
    __syncthreads();
  }
}

// ---------------- memory reader + loss — LDS serial; f32 loss to d_ws ----------------
__global__ __launch_bounds__(64) void k_loss(const u16* __restrict__ h,
    const int* __restrict__ topki, const int* __restrict__ query, const int* __restrict__ target,
    const float* __restrict__ qemb, const float* __restrict__ rq_w, const float* __restrict__ rq_b,
    const float* __restrict__ ro_w, const float* __restrict__ ro_b, float* __restrict__ loss_out){
  __shared__ float mvs[8][64];
  __shared__ float qhs[64], col[64], rds[64], lgs[64];
  __shared__ float scs[8];
  __shared__ float lossacc;
  const int lane = threadIdx.x;
  if (lane == 0) lossacc = 0.f;
  for (int b=0; b<BBATCH; b++){
    __syncthreads();
    #pragma unroll
    for (int m=0; m<8; m++){
      int idx = topki[b*8+m] & 2047;
      mvs[m][lane] = bfu2f(h[(size_t)(b*LQ + idx)*64 + lane]);
    }
    qhs[lane] = qemb[((query[b]&63)<<6) + lane];
    __syncthreads();
    float qd = rq_b[lane];
    for (int k=0;k<64;k++) qd += qhs[k] * rq_w[lane*64 + k];
    for (int m=0; m<8; m++){
      col[lane] = qd * mvs[m][lane];
      __syncthreads();
      if (lane == 0){
        float s = 0.f;
        for (int i2=0;i2<64;i2++) s += col[i2];
        scs[m] = s * 0.125f;   // 1/sqrt(64)
      }
      __syncthreads();
    }
    float mx = scs[0];
    #pragma unroll
    for (int m=1;m<8;m++) mx = fmaxf(mx, scs[m]);
    float wm[8]; float den = 0.f;
    #pragma unroll
    for (int m=0;m<8;m++){ wm[m] = __expf(scs[m]-mx); den += wm[m]; }
    float rd = 0.f;
    #pragma unroll
    for (int m=0;m<8;m++) rd += (wm[m]/den) * mvs[m][lane];
    rds[lane] = rd;
    __syncthreads();
    float lg = ro_b[lane];
    for (int d=0;d<64;d++) lg += rds[d] * ro_w[lane*64 + d];
    lgs[lane] = lg;
    __syncthreads();
    if (lane == 0){
      float lmx = lgs[0];
      for (int i2=1;i2<64;i2++) lmx = fmaxf(lmx, lgs[i2]);
      float es = 0.f;
      for (int i2=0;i2<64;i2++) es += __expf(lgs[i2]-lmx);
      float lt = lgs[target[b]&63];
      lossacc -= (lt - lmx - logf(es));
    }
  }
  __syncthreads();
  if (lane == 0) loss_out[0] = lossacc * (1.f/16.f);
}

// ---------------- final: f32 loss -> out_f[0] (runs LAST) ----------------
__global__ void k_store_loss(const float* __restrict__ ls, float* __restrict__ out){
  out[0] = ls[0];
}

// ---------------- launch ----------------
extern "C" void kernel_launch(void* const* d_in, const int* in_sizes, int n_in,
                              void* d_out, int out_size, void* d_ws, size_t ws_size,
                              hipStream_t stream){
  const int*   seq    = (const int*)  d_in[0];
  const int*   query  = (const int*)  d_in[1];
  const int*   target = (const int*)  d_in[2];
  const float* embed  = (const float*)d_in[3];
  const float* a1_wi  = (const float*)d_in[4];
  const float* a1_bi  = (const float*)d_in[5];
  const float* a1_wo  = (const float*)d_in[6];
  const float* a1_bo  = (const float*)d_in[7];
  const float* ff1_w1 = (const float*)d_in[8];
  const float* ff1_b1 = (const float*)d_in[9];
  const float* ff1_w2 = (const float*)d_in[10];
  const float* ff1_b2 = (const float*)d_in[11];
  const float* ln1a_g = (const float*)d_in[12];
  const float* ln1a_b = (const float*)d_in[13];
  const float* ln1b_g = (const float*)d_in[14];
  const float* ln1b_b = (const float*)d_in[15];
  const float* a2_wi  = (const float*)d_in[16];
  const float* a2_bi  = (const float*)d_in[17];
  const float* a2_wo  = (const float*)d_in[18];
  const float* a2_bo  = (const float*)d_in[19];
  const float* ff2_w1 = (const float*)d_in[20];
  const float* ff2_b1 = (const float*)d_in[21];
  const float* ff2_w2 = (const float*)d_in[22];
  const float* ff2_b2 = (const float*)d_in[23];
  const float* ln2a_g = (const float*)d_in[24];
  const float* ln2a_b = (const float*)d_in[25];
  const float* ln2b_g = (const float*)d_in[26];
  const float* ln2b_b = (const float*)d_in[27];
  const float* rq_w   = (const float*)d_in[28];
  const float* rq_b   = (const float*)d_in[29];
  const float* ro_w   = (const float*)d_in[30];
  const float* ro_b   = (const float*)d_in[31];
  const float* qemb   = (const float*)d_in[32];

  // d_ws (918,020 B)
  char* wsb      = (char*)d_ws;
  u16*  qk_ws    = (u16*)(wsb);                // 524,288 B (batch 15 [Qs|K])
  float* ws_imp  = (float*)(wsb + 524288);     // 131,072 B
  float* ws_l    = (float*)(wsb + 655360);     // 262,144 B
  int*  ws_top   = (int*)(wsb + 917504);       // 512 B
  float* ws_loss = (float*)(wsb + 918016);     // 4 B

  // d_out (FLOAT32, 268,435,460 B) + scratch parking
  float* out_f  = (float*)d_out;
  u16* h16     = (u16*)((char*)d_out + 64);          // 4 MB bf16, region 0
  u16* qk1     = (u16*)((char*)d_out + 4194368);     // 8 MB layer-1 [Qs|K]
  u16* vg1     = (u16*)((char*)d_out + 12582976);    // 4 MB layer-1 V (j-tiled)
  u16* vg2     = (u16*)((char*)d_out + 4194368);     // 4 MB layer-2 V (j-tiled)
  u16* qk_r15  = (u16*)((char*)d_out + 251658304);   // 7.7 MB, region 15

  k_embed<<<8192,256,0,stream>>>(seq, embed, h16);
  k_zero<<<128,256,0,stream>>>(ws_imp);
  // layer 1
  k_qkv<0><<<2048,256,0,stream>>>(h16, a1_wi, a1_bi, qk1, nullptr, nullptr, vg1);
  k_attn_ln<0><<<dim3(32,16),256,0,stream>>>(qk1, nullptr, vg1,
                                             a1_wo, a1_bo, ln1a_g, ln1a_b, h16, nullptr);
  k_ffn<<<2048,256,0,stream>>>(h16, ff1_w1, ff1_b1, ff1_w2, ff1_b2, ln1b_g, ln1b_b);
  // layer 2
  k_qkv<1><<<2048,256,0,stream>>>(h16, a2_wi, a2_bi, nullptr, qk_r15, qk_ws, vg2);
  k_attn_ln<1><<<dim3(32,16),256,0,stream>>>(qk_r15, qk_ws, vg2,
                                             a2_wo, a2_bo, ln2a_g, ln2a_b, h16, ws_l);
  k_ffn<<<2048,256,0,stream>>>(h16, ff2_w1, ff2_b1, ff2_w2, ff2_b2, ln2b_g, ln2b_b);
  // importance -> topk -> loss (loss to d_ws; h16 still alive)
  k_imp<<<dim3(32,16),256,0,stream>>>(qk_r15, qk_ws, ws_l, ws_imp);
  k_topk<<<16,64,0,stream>>>(ws_imp, ws_top);
  k_loss<<<1,64,0,stream>>>(h16, ws_top, query, target, qemb, rq_w, rq_b, ro_w, ro_b, ws_loss);
  // attn_w FLOAT32 (destroys d_out scratch): wave1 b0-14, wave2 b15
  k_pass2<<<dim3(32,15),256,0,stream>>>(qk_r15, qk_ws, ws_l, out_f, 0);
  k_pass2<<<dim3(32,1),256,0,stream>>>(qk_r15, qk_ws, ws_l, out_f, 15);
  // loss stored LAST
  k_store_loss<<<1,1,0,stream>>>(ws_loss, out_f);
}

// Round 2
// 1180.123 us; speedup vs baseline: 2.5067x; 1.4993x over previous
//
#include <hip/hip_runtime.h>
#include <hip/hip_bf16.h>

// RecallModel: B=16, L=2048, H=64, NH=2, HD=32, M=8, V=64.
// Inputs: ints int32; floats FP32. OUTPUTS FLOAT32 (reference dtype!):
//   out_f[0] = loss, out_f[1..1+16*2048*2048) = attn_w (B,L,L). 268,435,460 B.
//
// d_ws usage: 918,020 bytes:
//   qk15 @0       524,288 B  bf16 [Qs|K] batch 15 (layer 2)
//   imp  @524288  131,072 B  f32 imp[16][2048]
//   l2   @655360  262,144 B  f32 sum-of-exp
//   topk @917504      512 B
//   loss @918016        4 B  f32
// d_out doubles as scratch (dead-before-overwrite). attn batch-b region =
// bytes [4 + b*16777216, 4 + (b+1)*16777216).
//   h      @ byte 64         4 MB bf16 (region 0; dies at k_loss, before pass2)
//   qk1    @ byte 4194368    8 MB bf16 layer-1 [Qs|K] rows s128 (dies at attn1)
//   vg1    @ byte 12582976   4 MB bf16 layer-1 V, j-tiled (dies at attn1;
//                                 60 B spill into region 1 is dead too)
//   vg2    @ byte 4194368    4 MB bf16 layer-2 V, j-tiled (dies at attn2)
//   qk0-14 @ byte 251658304  7.7 MB (region 15; dies at pass2 wave2)
// pass2 wave1 (bz 0..14) writes regions 0..14 (reads park in region 15);
// wave2 (bz 15) reads d_ws, overwrites region 15. Loss stored LAST to out_f[0].
//
// V j-tiled layout (per batch): element (j,d) at
//   ((( (j>>5)*4 + ((j>>2)&3) )*64 + d)*8 + ((j>>4)&1)*4 + (j&3)
// so the PV B-fragment (lane g: j in {J0+4g..+3} u {J0+16+4g..+3}) is ONE
// contiguous 16 B load per lane (coalesced 256 B per 16-lane group).

typedef unsigned short u16;
#define LQ 2048
#define BBATCH 16
#define QKB 262144   // u16 elements per batch of packed [Qs|K] (2048*128)

typedef __attribute__((ext_vector_type(8))) short bf16x8;
typedef __attribute__((ext_vector_type(4))) float f32x4;

__device__ __forceinline__ float bfu2f(u16 x){ return __uint_as_float(((unsigned)x) << 16); }
__device__ __forceinline__ u16 f2bu(float f){ return __bfloat16_as_ushort(__float2bfloat16(f)); }

__device__ __forceinline__ const u16* qk_rowp(const u16* qk_r15, const u16* qk_ws,
                                              int bz, int row){
  const u16* base = (bz < 15) ? (qk_r15 + (size_t)bz*QKB) : qk_ws;
  return base + (size_t)row*128;
}
__device__ __forceinline__ u16* qk_rowp_w(u16* qk_r15, u16* qk_ws, int bz, int row){
  u16* base = (bz < 15) ? (qk_r15 + (size_t)bz*QKB) : qk_ws;
  return base + (size_t)row*128;
}

// ---------------- embed ----------------
__global__ __launch_bounds__(256) void k_embed(const int* __restrict__ seq,
                                               const float* __restrict__ emb,
                                               u16* __restrict__ h){
  int i = blockIdx.x*256 + threadIdx.x;      // 32768*64
  int tok = i >> 6, d = i & 63;
  int v = seq[tok] & 63;
  h[i] = f2bu(emb[(v << 6) + d]);
}

__global__ __launch_bounds__(256) void k_zero(float* __restrict__ p, float* __restrict__ q){
  int i = blockIdx.x*256 + threadIdx.x;
  p[i] = 0.f;
  if (i == 0) q[0] = 0.f;
}

// ---------------- qkv projection ----------------
// Writes [Qs|K] rows (stride 128 u16) + V in j-tiled layout (see header).
template<int MODE>
__global__ __launch_bounds__(256) void k_qkv(const u16* __restrict__ X,
                                             const float* __restrict__ W,
                                             const float* __restrict__ bias,
                                             u16* __restrict__ dqk0,
                                             u16* __restrict__ dqk_r15,
                                             u16* __restrict__ dqk_ws,
                                             u16* __restrict__ vg){
  __shared__ float WT[64*193];   // [k][mo]
  __shared__ float bs[192];
  const int t = threadIdx.x;
  for (int e=t; e<192*64; e+=256){ int mo=e>>6, k=e&63; WT[k*193+mo] = W[e]; }
  if (t < 192) bs[t] = bias[t];
  __syncthreads();
  const int wid=t>>6, lane=t&63;
  const int tok0 = (blockIdx.x*4 + wid)*4;
  float x[4];
  #pragma unroll
  for (int c=0;c<4;c++) x[c] = bfu2f(X[(tok0+c)*64 + lane]);
  float acc[4][3];
  #pragma unroll
  for (int c=0;c<4;c++)
    #pragma unroll
    for (int m=0;m<3;m++) acc[c][m] = bs[m*64 + lane];
  for (int k=0;k<64;k++){
    float wv[3];
    #pragma unroll
    for (int m=0;m<3;m++) wv[m] = WT[k*193 + m*64 + lane];
    #pragma unroll
    for (int c=0;c<4;c++){
      float xk = __shfl(x[c], k);
      #pragma unroll
      for (int m=0;m<3;m++) acc[c][m] += xk*wv[m];
    }
  }
  const float qs = 0.17677669529663688f;  // 1/sqrt(32)
  #pragma unroll
  for (int c=0;c<4;c++){
    int tok = tok0+c;
    float vq = acc[c][0]*qs, vk = acc[c][1], vv = acc[c][2];
    int b = tok >> 11, r = tok & 2047;
    u16* row = (MODE==0) ? (dqk0 + (size_t)tok*128) : qk_rowp_w(dqk_r15, dqk_ws, b, r);
    row[lane]      = f2bu(vq);
    row[64 + lane] = f2bu(vk);
    vg[((size_t)((b*64 + (r>>5))*4 + ((r>>2)&3))*64 + lane)*8
       + ((r>>4)&1)*4 + (r&3)] = f2bu(vv);
  }
}

// ---------------- attention (MFMA) + fused proj+residual+LN ----------------
// One block = 64 q-rows, one wave = 16 q-rows. Per k-tile (64 keys), per head:
//   S^T tiles:  D = mfma(K_frag, Q_frag)  -> lane holds S^T[j][q], q = wv*16+n
//   exp in f32, denominator accumulates in-register
//   P (bf16) is re-packed IN-LANE as the PV A-fragment (k-slot map
//   j = 16*(2kb+s/4)+4g+s%4, identical on the V B-fragment side -> exact).
// No LDS, no barriers in the main loop. K frags from [Qs|K] rows (L1-shared),
// V frags from j-tiled global (coalesced 16 B/lane).
template<int MODE>
__global__ __launch_bounds__(256) void k_attn_ln(const u16* __restrict__ PQK,
    const u16* __restrict__ QKWS, const u16* __restrict__ VG,
    const float* __restrict__ wo, const float* __restrict__ bo,
    const float* __restrict__ g, const float* __restrict__ be,
    u16* __restrict__ h, float* __restrict__ lout){
  __shared__ float sm[8768];         // 35072 B
  float* ST  = sm;                   // [64][68] attn output (f32, padded)
  float* WOT = sm + 4352;            // [64][64] wo^T
  float* CB  = sm + 8448;            // 192: bo | g | be
  float* LAC = sm + 8640;            // 128: per-head softmax denominators
  const int t = threadIdx.x;
  const int qt = blockIdx.x, bz = blockIdx.y;
  const int lane = t & 63, wv = t >> 6;
  const int n = lane & 15, gq = lane >> 4;
  const f32x4 FZ = {0.f, 0.f, 0.f, 0.f};

  // Q fragments: row q = qt*64 + wv*16 + n, d-slots = hh*32 + gq*8 .. +8
  bf16x8 qf[2];
  {
    const u16* qrow = (MODE==0) ? (PQK + (size_t)(bz*LQ + qt*64 + wv*16 + n)*128)
                                : qk_rowp(PQK, QKWS, bz, qt*64 + wv*16 + n);
    qf[0] = *(const bf16x8*)(qrow + gq*8);
    qf[1] = *(const bf16x8*)(qrow + 32 + gq*8);
  }
  f32x4 o[2][2];
  #pragma unroll
  for (int hh=0; hh<2; hh++)
    #pragma unroll
    for (int db=0; db<2; db++) o[hh][db] = FZ;
  float dacc[2] = {0.f, 0.f};

  for (int kt=0; kt<32; kt++){
    #pragma unroll
    for (int hh=0; hh<2; hh++){
      // S^T: lane (gq,n) gets S^T[j = kt*64+jb*16+4gq+reg][q = wv*16+n]
      f32x4 ev[4];
      #pragma unroll
      for (int jb=0; jb<4; jb++){
        const u16* kr = (MODE==0) ? (PQK + (size_t)(bz*LQ + kt*64 + jb*16 + n)*128)
                                  : qk_rowp(PQK, QKWS, bz, kt*64 + jb*16 + n);
        bf16x8 kf = *(const bf16x8*)(kr + 64 + hh*32 + gq*8);
        ev[jb] = __builtin_amdgcn_mfma_f32_16x16x32_bf16(kf, qf[hh], FZ, 0, 0, 0);
      }
      unsigned pk[4][2];
      float ds = 0.f;
      #pragma unroll
      for (int jb=0; jb<4; jb++){
        float e0 = __expf(ev[jb][0]), e1 = __expf(ev[jb][1]);
        float e2 = __expf(ev[jb][2]), e3 = __expf(ev[jb][3]);
        ds += (e0+e1) + (e2+e3);
        pk[jb][0] = (unsigned)f2bu(e0) | ((unsigned)f2bu(e1) << 16);
        pk[jb][1] = (unsigned)f2bu(e2) | ((unsigned)f2bu(e3) << 16);
      }
      dacc[hh] += ds;
      #pragma unroll
      for (int kb=0; kb<2; kb++){
        union { unsigned u[4]; bf16x8 v; } af;    // PV A-frag from own E's
        af.u[0] = pk[2*kb][0];   af.u[1] = pk[2*kb][1];
        af.u[2] = pk[2*kb+1][0]; af.u[3] = pk[2*kb+1][1];
        #pragma unroll
        for (int db=0; db<2; db++){
          const int d = hh*32 + db*16 + n;
          const bf16x8 vf = *(const bf16x8*)(VG +
              ((size_t)((bz*64 + kt*2 + kb)*4 + gq)*64 + d)*8);
          o[hh][db] = __builtin_amdgcn_mfma_f32_16x16x32_bf16(af.v, vf, o[hh][db], 0, 0, 0);
        }
      }
    }
  }
  // softmax denominators: reduce partial sums across the 4 gq groups
  #pragma unroll
  for (int hh=0; hh<2; hh++){
    float s = dacc[hh];
    s += __shfl_xor(s, 16);
    s += __shfl_xor(s, 32);
    if (gq == 0){
      LAC[hh*64 + wv*16 + n] = s;
      if (lout) lout[(size_t)(bz*2 + hh)*LQ + qt*64 + wv*16 + n] = s;
    }
  }
  __syncthreads();
  // normalize O -> ST[q][d] (stride 68); lane holds O[q=wv*16+4gq+r][d=hh*32+db*16+n]
  #pragma unroll
  for (int hh=0; hh<2; hh++){
    #pragma unroll
    for (int r=0; r<4; r++){
      const int q = wv*16 + gq*4 + r;
      float il = 1.f / LAC[hh*64 + q];
      ST[q*68 + hh*32 + n]      = o[hh][0][r] * il;
      ST[q*68 + hh*32 + 16 + n] = o[hh][1][r] * il;
    }
  }
  for (int e2=t; e2<4096; e2+=256){ int k=e2>>6, mo=e2&63; WOT[e2] = wo[mo*64+k]; }
  if (t < 64)       CB[t] = bo[t];
  else if (t < 128) CB[t] = g[t-64];
  else if (t < 192) CB[t] = be[t-128];
  __syncthreads();
  // proj + residual + LN
  for (int r=0; r<16; r++){
    int tl = wv*16 + r;
    size_t gtok = (size_t)(bz*LQ + qt*64 + tl);
    float acc = CB[lane];
    for (int k=0; k<64; k++) acc += ST[tl*68 + k] * WOT[k*64 + lane];
    float rr = acc + bfu2f(h[gtok*64 + lane]);
    float s = rr;
    #pragma unroll
    for (int ofs=32; ofs; ofs>>=1) s += __shfl_xor(s, ofs);
    float mean = s * (1.f/64.f);
    float dv = rr - mean;
    float vs = dv*dv;
    #pragma unroll
    for (int ofs=32; ofs; ofs>>=1) vs += __shfl_xor(vs, ofs);
    float rstd = 1.f/sqrtf(vs*(1.f/64.f) + 1e-5f);
    h[gtok*64 + lane] = f2bu(dv*rstd*CB[64+lane] + CB[128+lane]);
  }
}

// ---------------- fused FFN + residual + LN ----------------
__global__ __launch_bounds__(256) void k_ffn(u16* __restrict__ h,
    const float* __restrict__ w1, const float* __restrict__ b1,
    const float* __restrict__ w2, const float* __restrict__ b2,
    const float* __restrict__ g, const float* __restrict__ be){
  __shared__ u16 W1u[64*128];
  __shared__ u16 W2u[128*64];
  __shared__ float B1[128], B2[64], G[64], Bb[64];
  const int t = threadIdx.x;
  for (int e=t; e<8192; e+=256){ int k=e>>7, mo=e&127; W1u[e] = f2bu(w1[mo*64+k]); }
  for (int e=t; e<8192; e+=256){ int k=e>>6, mo=e&63;  W2u[e] = f2bu(w2[mo*128+k]); }
  if (t < 128) B1[t] = b1[t];
  if (t < 64){ B2[t] = b2[t]; G[t] = g[t]; Bb[t] = be[t]; }
  __syncthreads();
  const int wid = t >> 6, lane = t & 63;
  const int tok0 = (blockIdx.x*4 + wid)*4;
  float x[4];
  #pragma unroll
  for (int c=0;c<4;c++) x[c] = bfu2f(h[(tok0+c)*64 + lane]);
  #pragma unroll
  for (int c=0;c<4;c++){
    float a = B1[lane], b = B1[64+lane];
    for (int k=0;k<64;k++){
      float xk = __shfl(x[c], k);
      a += xk * bfu2f(W1u[k*128 + lane]);
      b += xk * bfu2f(W1u[k*128 + 64 + lane]);
    }
    a = fmaxf(a, 0.f); b = fmaxf(b, 0.f);
    float acc = B2[lane];
    for (int k=0;k<64;k++) acc += __shfl(a,k) * bfu2f(W2u[k*64 + lane]);
    for (int k=0;k<64;k++) acc += __shfl(b,k) * bfu2f(W2u[(64+k)*64 + lane]);
    float rr = acc + x[c];
    float s = rr;
    #pragma unroll
    for (int o=32;o;o>>=1) s += __shfl_xor(s,o);
    float mean = s * (1.f/64.f);
    float dv = rr - mean;
    float vs = dv*dv;
    #pragma unroll
    for (int o=32;o;o>>=1) vs += __shfl_xor(vs,o);
    float rstd = 1.f/sqrtf(vs*(1.f/64.f) + 1e-5f);
    h[(tok0+c)*64 + lane] = f2bu(dv*rstd*G[lane] + Bb[lane]);
  }
}

// ---------------- importance (MFMA): recompute scores, column-sum ----------------
// mfma(Q_frag, K_frag): lane (gq,n) reg r holds S[q = wv*16+4gq+r][j = jb*16+n]
// -> 4 in-lane adds + shfl_xor(16,32) = column sum over the wave's 16 q rows.
__global__ __launch_bounds__(256) void k_imp(const u16* __restrict__ qk_r15,
    const u16* __restrict__ qk_ws, const float* __restrict__ l2,
    float* __restrict__ imp){
  __shared__ float IMPS[2048];
  __shared__ float INVL[128];
  const int t = threadIdx.x;
  const int qt = blockIdx.x, bz = blockIdx.y;
  const int lane = t & 63, wv = t >> 6;
  const int n = lane & 15, gq = lane >> 4;
  const f32x4 FZ = {0.f, 0.f, 0.f, 0.f};
  if (t < 128) INVL[t] = 1.f / l2[(size_t)(bz*2 + (t>>6))*LQ + qt*64 + (t&63)];
  for (int e=t; e<2048; e+=256) IMPS[e] = 0.f;
  bf16x8 qf0, qf1;
  {
    const u16* qrow = qk_rowp(qk_r15, qk_ws, bz, qt*64 + wv*16 + n);
    qf0 = *(const bf16x8*)(qrow + gq*8);
    qf1 = *(const bf16x8*)(qrow + 32 + gq*8);
  }
  __syncthreads();
  float iv0[4], iv1[4];
  #pragma unroll
  for (int r=0;r<4;r++){
    iv0[r] = INVL[wv*16 + gq*4 + r];
    iv1[r] = INVL[64 + wv*16 + gq*4 + r];
  }
  for (int kt=0; kt<32; kt++){
    #pragma unroll
    for (int jb=0; jb<4; jb++){
      const u16* kr = qk_rowp(qk_r15, qk_ws, bz, kt*64 + jb*16 + n);
      bf16x8 kf0 = *(const bf16x8*)(kr + 64 + gq*8);
      bf16x8 kf1 = *(const bf16x8*)(kr + 96 + gq*8);
      f32x4 e0 = __builtin_amdgcn_mfma_f32_16x16x32_bf16(qf0, kf0, FZ, 0, 0, 0);
      f32x4 e1 = __builtin_amdgcn_mfma_f32_16x16x32_bf16(qf1, kf1, FZ, 0, 0, 0);
      float cs = 0.f;
      #pragma unroll
      for (int r=0;r<4;r++)
        cs += 0.5f*(__expf(e0[r])*iv0[r] + __expf(e1[r])*iv1[r]);
      cs += __shfl_xor(cs, 16);
      cs += __shfl_xor(cs, 32);
      if (gq == 0) atomicAdd(&IMPS[kt*64 + jb*16 + n], cs);
    }
  }
  __syncthreads();
  for (int e=t; e<2048; e+=256) atomicAdd(&imp[bz*LQ + e], IMPS[e]);
}

// ---------------- pass2 (MFMA): recompute scores, write attn_w FLOAT32 ------
// Grid (256, nb): blockIdx.x = qt*8 + ks; block covers q-tile qt (64 rows) and
// k-tiles kt = ks*4 .. ks*4+4. Per wave: own 16 q rows, all 64 j of the tile.
// S^T from mfma(K_frag, Q_frag); stage per-wave-private STG rows; write
// 256 B-contiguous rows. No barriers in the main loop.
__global__ __launch_bounds__(256) void k_pass2(const u16* __restrict__ qk_r15,
    const u16* __restrict__ qk_ws, const float* __restrict__ l2,
    float* __restrict__ wout, int bz0){
  __shared__ float STG[64*68];       // [q][j] staging, per-wave-private rows
  __shared__ float INVL[128];
  const int t = threadIdx.x;
  const int qt = blockIdx.x >> 3, ks = blockIdx.x & 7;
  const int bz = bz0 + blockIdx.y;
  const int lane = t & 63, wv = t >> 6;
  const int n = lane & 15, gq = lane >> 4;
  const f32x4 FZ = {0.f, 0.f, 0.f, 0.f};
  if (t < 128) INVL[t] = 1.f / l2[(size_t)(bz*2 + (t>>6))*LQ + qt*64 + (t&63)];
  bf16x8 qf0, qf1;
  {
    const u16* qrow = qk_rowp(qk_r15, qk_ws, bz, qt*64 + wv*16 + n);
    qf0 = *(const bf16x8*)(qrow + gq*8);
    qf1 = *(const bf16x8*)(qrow + 32 + gq*8);
  }
  __syncthreads();
  const float iv0 = INVL[wv*16 + n], iv1 = INVL[64 + wv*16 + n];
  for (int kt = ks*4; kt < ks*4 + 4; kt++){
    #pragma unroll
    for (int jb=0; jb<4; jb++){
      const u16* kr = qk_rowp(qk_r15, qk_ws, bz, kt*64 + jb*16 + n);
      bf16x8 kf0 = *(const bf16x8*)(kr + 64 + gq*8);
      bf16x8 kf1 = *(const bf16x8*)(kr + 96 + gq*8);
      f32x4 e0 = __builtin_amdgcn_mfma_f32_16x16x32_bf16(kf0, qf0, FZ, 0, 0, 0);
      f32x4 e1 = __builtin_amdgcn_mfma_f32_16x16x32_bf16(kf1, qf1, FZ, 0, 0, 0);
      // lane (gq,n) reg r: w[q = wv*16+n][j = jb*16+4gq+r]
      float4 w4;
      w4.x = 0.5f*(__expf(e0[0])*iv0 + __expf(e1[0])*iv1);
      w4.y = 0.5f*(__expf(e0[1])*iv0 + __expf(e1[1])*iv1);
      w4.z = 0.5f*(__expf(e0[2])*iv0 + __expf(e1[2])*iv1);
      w4.w = 0.5f*(__expf(e0[3])*iv0 + __expf(e1[3])*iv1);
      *(float4*)(&STG[(wv*16 + n)*68 + jb*16 + 4*gq]) = w4;
    }
    size_t base = 1 + (size_t)bz*LQ*LQ + (size_t)(qt*64)*LQ + (size_t)kt*64;
    for (int r=0; r<16; r++){
      int q = wv*16 + r;
      wout[base + (size_t)q*LQ + lane] = STG[q*68 + lane];
    }
  }
}

// ---------------- top-k (M=8, ties -> lowest index) — LDS serial ----------------
__global__ __launch_bounds__(64) void k_topk(const float* __restrict__ imp,
                                             int* __restrict__ topki){
  __shared__ float v[2048];
  __shared__ float bv[64];
  __shared__ int   bi[64];
  __shared__ int   chosen;
  const int b = blockIdx.x, lane = threadIdx.x;
  for (int i=lane; i<2048; i+=64) v[i] = imp[b*2048 + i];
  __syncthreads();
  for (int m=0; m<8; m++){
    float best = -1e30f; int besti = 1<<30;
    for (int i=lane; i<2048; i+=64)
      if (v[i] > best || (v[i] == best && i < besti)){ best = v[i]; besti = i; }
    bv[lane] = best; bi[lane] = besti;
    __syncthreads();
    if (lane == 0){
      float B = bv[0]; int I = bi[0];
      for (int i2=1; i2<64; i2++)
        if (bv[i2] > B || (bv[i2] == B && bi[i2] < I)){ B = bv[i2]; I = bi[i2]; }
      topki[b*8 + m] = (I < 0) ? 0 : (I > 2047 ? 2047 : I);
      chosen = (I < 0) ? 0 : (I > 2047 ? 2047 : I);
    }
    __syncthreads();
    if (lane == 0) v[chosen] = -1e30f;
    __syncthreads();
  }
}

// ---------------- memory reader + loss — one block per batch, wave-parallel ----
__global__ __launch_bounds__(64) void k_loss(const u16* __restrict__ h,
    const int* __restrict__ topki, const int* __restrict__ query, const int* __restrict__ target,
    const float* __restrict__ qemb, const float* __restrict__ rq_w, const float* __restrict__ rq_b,
    const float* __restrict__ ro_w, const float* __restrict__ ro_b, float* __restrict__ loss_out){
  const int b = blockIdx.x, lane = threadIdx.x;
  float mv[8];
  #pragma unroll
  for (int m=0; m<8; m++){
    int idx = topki[b*8+m] & 2047;
    mv[m] = bfu2f(h[(size_t)(b*LQ + idx)*64 + lane]);
  }
  float qh = qemb[((query[b]&63)<<6) + lane];
  float qd = rq_b[lane];
  for (int k=0;k<64;k++) qd += __shfl(qh,k) * rq_w[lane*64 + k];
  float sc[8];
  #pragma unroll
  for (int m=0;m<8;m++){
    float p = qd * mv[m];
    #pragma unroll
    for (int o=32;o;o>>=1) p += __shfl_xor(p,o);
    sc[m] = p * 0.125f;   // 1/sqrt(64)
  }
  float mx = sc[0];
  #pragma unroll
  for (int m=1;m<8;m++) mx = fmaxf(mx, sc[m]);
  float den = 0.f, rd = 0.f;
  #pragma unroll
  for (int m=0;m<8;m++){ float w = __expf(sc[m]-mx); den += w; rd += w*mv[m]; }
  rd /= den;
  float lg = ro_b[lane];
  for (int d=0;d<64;d++) lg += __shfl(rd,d) * ro_w[lane*64 + d];
  float lmx = lg;
  #pragma unroll
  for (int o=32;o;o>>=1) lmx = fmaxf(lmx, __shfl_xor(lmx,o));
  float ex = __expf(lg - lmx), es = ex;
  #pragma unroll
  for (int o=32;o;o>>=1) es += __shfl_xor(es,o);
  float lt = __shfl(lg, target[b]&63);
  if (lane == 0) atomicAdd(loss_out, -(lt - lmx - logf(es)) * (1.f/16.f));
}

// ---------------- final: f32 loss -> out_f[0] (runs LAST) ----------------
__global__ void k_store_loss(const float* __restrict__ ls, float* __restrict__ out){
  out[0] = ls[0];
}

// ---------------- launch ----------------
extern "C" void kernel_launch(void* const* d_in, const int* in_sizes, int n_in,
                              void* d_out, int out_size, void* d_ws, size_t ws_size,
                              hipStream_t stream){
  const int*   seq    = (const int*)  d_in[0];
  const int*   query  = (const int*)  d_in[1];
  const int*   target = (const int*)  d_in[2];
  const float* embed  = (const float*)d_in[3];
  const float* a1_wi  = (const float*)d_in[4];
  const float* a1_bi  = (const float*)d_in[5];
  const float* a1_wo  = (const float*)d_in[6];
  const float* a1_bo  = (const float*)d_in[7];
  const float* ff1_w1 = (const float*)d_in[8];
  const float* ff1_b1 = (const float*)d_in[9];
  const float* ff1_w2 = (const float*)d_in[10];
  const float* ff1_b2 = (const float*)d_in[11];
  const float* ln1a_g = (const float*)d_in[12];
  const float* ln1a_b = (const float*)d_in[13];
  const float* ln1b_g = (const float*)d_in[14];
  const float* ln1b_b = (const float*)d_in[15];
  const float* a2_wi  = (const float*)d_in[16];
  const float* a2_bi  = (const float*)d_in[17];
  const float* a2_wo  = (const float*)d_in[18];
  const float* a2_bo  = (const float*)d_in[19];
  const float* ff2_w1 = (const float*)d_in[20];
  const float* ff2_b1 = (const float*)d_in[21];
  const float* ff2_w2 = (const float*)d_in[22];
  const float* ff2_b2 = (const float*)d_in[23];
  const float* ln2a_g = (const float*)d_in[24];
  const float* ln2a_b = (const float*)d_in[25];
  const float* ln2b_g = (const float*)d_in[26];
  const float* ln2b_b = (const float*)d_in[27];
  const float* rq_w   = (const float*)d_in[28];
  const float* rq_b   = (const float*)d_in[29];
  const float* ro_w   = (const float*)d_in[30];
  const float* ro_b   = (const float*)d_in[31];
  const float* qemb   = (const float*)d_in[32];

  // d_ws (918,020 B)
  char* wsb      = (char*)d_ws;
  u16*  qk_ws    = (u16*)(wsb);                // 524,288 B (batch 15 [Qs|K])
  float* ws_imp  = (float*)(wsb + 524288);     // 131,072 B
  float* ws_l    = (float*)(wsb + 655360);     // 262,144 B
  int*  ws_top   = (int*)(wsb + 917504);       // 512 B
  float* ws_loss = (float*)(wsb + 918016);     // 4 B

  // d_out (FLOAT32, 268,435,460 B) + scratch parking
  float* out_f  = (float*)d_out;
  u16* h16     = (u16*)((char*)d_out + 64);          // 4 MB bf16, region 0
  u16* qk1     = (u16*)((char*)d_out + 4194368);     // 8 MB layer-1 [Qs|K]
  u16* vg1     = (u16*)((char*)d_out + 12582976);    // 4 MB layer-1 V (j-tiled)
  u16* vg2     = (u16*)((char*)d_out + 4194368);     // 4 MB layer-2 V (j-tiled)
  u16* qk_r15  = (u16*)((char*)d_out + 251658304);   // 7.7 MB, region 15

  k_embed<<<8192,256,0,stream>>>(seq, embed, h16);
  k_zero<<<128,256,0,stream>>>(ws_imp, ws_loss);
  // layer 1
  k_qkv<0><<<2048,256,0,stream>>>(h16, a1_wi, a1_bi, qk1, nullptr, nullptr, vg1);
  k_attn_ln<0><<<dim3(32,16),256,0,stream>>>(qk1, nullptr, vg1,
                                             a1_wo, a1_bo, ln1a_g, ln1a_b, h16, nullptr);
  k_ffn<<<2048,256,0,stream>>>(h16, ff1_w1, ff1_b1, ff1_w2, ff1_b2, ln1b_g, ln1b_b);
  // layer 2
  k_qkv<1><<<2048,256,0,stream>>>(h16, a2_wi, a2_bi, nullptr, qk_r15, qk_ws, vg2);
  k_attn_ln<1><<<dim3(32,16),256,0,stream>>>(qk_r15, qk_ws, vg2,
                                             a2_wo, a2_bo, ln2a_g, ln2a_b, h16, ws_l);
  k_ffn<<<2048,256,0,stream>>>(h16, ff2_w1, ff2_b1, ff2_w2, ff2_b2, ln2b_g, ln2b_b);
  // importance -> topk -> loss (loss to d_ws; h16 still alive)
  k_imp<<<dim3(32,16),256,0,stream>>>(qk_r15, qk_ws, ws_l, ws_imp);
  k_topk<<<16,64,0,stream>>>(ws_imp, ws_top);
  k_loss<<<16,64,0,stream>>>(h16, ws_top, query, target, qemb, rq_w, rq_b, ro_w, ro_b, ws_loss);
  // attn_w FLOAT32 (destroys d_out scratch): wave1 b0-14, wave2 b15
  k_pass2<<<dim3(256,15),256,0,stream>>>(qk_r15, qk_ws, ws_l, out_f, 0);
  k_pass2<<<dim3(256,1),256,0,stream>>>(qk_r15, qk_ws, ws_l, out_f, 15);
  // loss stored LAST
  k_store_loss<<<1,1,0,stream>>>(ws_loss, out_f);
}

// Round 3
// 1062.740 us; speedup vs baseline: 2.7836x; 1.1105x over previous
//
#include <hip/hip_runtime.h>
#include <hip/hip_bf16.h>

// RecallModel: B=16, L=2048, H=64, NH=2, HD=32, M=8, V=64.
// Inputs: ints int32; floats FP32. OUTPUTS FLOAT32 (reference dtype!):
//   out_f[0] = loss, out_f[1..1+16*2048*2048) = attn_w (B,L,L). 268,435,460 B.
//
// d_ws usage: 918,020 bytes:
//   qk15 @0       524,288 B  bf16 [Qs|K] batch 15 (layer 2)
//   imp  @524288  131,072 B  f32 imp[16][2048]
//   l2   @655360  262,144 B  f32 sum-of-exp
//   topk @917504      512 B
//   loss @918016        4 B  f32
// d_out doubles as scratch (dead-before-overwrite). attn batch-b region =
// bytes [4 + b*16777216, 4 + (b+1)*16777216).
//   h      @ byte 64         4 MB bf16 (region 0; dies at k_loss, before pass2)
//   qk1    @ byte 4194368    8 MB bf16 layer-1 [Qs|K] rows s128 (dies at attn1)
//   vg1    @ byte 12582976   4 MB bf16 layer-1 V, j-tiled (dies at attn1;
//                                 60 B spill into region 1 is dead too)
//   vg2    @ byte 4194368    4 MB bf16 layer-2 V, j-tiled (dies at attn2)
//   qk0-14 @ byte 251658304  7.7 MB (region 15; dies at pass2 wave2)
// pass2 wave1 (bz 0..14) writes regions 0..14 (reads park in region 15);
// wave2 (bz 15) reads d_ws, overwrites region 15. Loss stored LAST to out_f[0].
//
// V j-tiled layout (per batch): element (j,d) at
//   ((( (j>>5)*4 + ((j>>2)&3) )*64 + d)*8 + ((j>>4)&1)*4 + (j&3)
// so the PV B-fragment (lane g: j in {J0+4g..+3} u {J0+16+4g..+3}) is ONE
// contiguous 16 B load per lane (coalesced 256 B per 16-lane group).

typedef unsigned short u16;
#define LQ 2048
#define BBATCH 16
#define QKB 262144   // u16 elements per batch of packed [Qs|K] (2048*128)

typedef __attribute__((ext_vector_type(8))) short bf16x8;
typedef __attribute__((ext_vector_type(4))) float f32x4;

__device__ __forceinline__ float bfu2f(u16 x){ return __uint_as_float(((unsigned)x) << 16); }
__device__ __forceinline__ u16 f2bu(float f){ return __bfloat16_as_ushort(__float2bfloat16(f)); }

__device__ __forceinline__ const u16* qk_rowp(const u16* qk_r15, const u16* qk_ws,
                                              int bz, int row){
  const u16* base = (bz < 15) ? (qk_r15 + (size_t)bz*QKB) : qk_ws;
  return base + (size_t)row*128;
}
__device__ __forceinline__ u16* qk_rowp_w(u16* qk_r15, u16* qk_ws, int bz, int row){
  u16* base = (bz < 15) ? (qk_r15 + (size_t)bz*QKB) : qk_ws;
  return base + (size_t)row*128;
}

// ---------------- embed ----------------
__global__ __launch_bounds__(256) void k_embed(const int* __restrict__ seq,
                                               const float* __restrict__ emb,
                                               u16* __restrict__ h){
  int i = blockIdx.x*256 + threadIdx.x;      // 32768*64
  int tok = i >> 6, d = i & 63;
  int v = seq[tok] & 63;
  h[i] = f2bu(emb[(v << 6) + d]);
}

__global__ __launch_bounds__(256) void k_zero(float* __restrict__ p, float* __restrict__ q){
  int i = blockIdx.x*256 + threadIdx.x;
  p[i] = 0.f;
  if (i == 0) q[0] = 0.f;
}

// ---------------- qkv projection ----------------
// Writes [Qs|K] rows (stride 128 u16) + V in j-tiled layout (see header).
template<int MODE>
__global__ __launch_bounds__(256) void k_qkv(const u16* __restrict__ X,
                                             const float* __restrict__ W,
                                             const float* __restrict__ bias,
                                             u16* __restrict__ dqk0,
                                             u16* __restrict__ dqk_r15,
                                             u16* __restrict__ dqk_ws,
                                             u16* __restrict__ vg){
  __shared__ float WT[64*193];   // [k][mo]
  __shared__ float bs[192];
  const int t = threadIdx.x;
  for (int e=t; e<192*64; e+=256){ int mo=e>>6, k=e&63; WT[k*193+mo] = W[e]; }
  if (t < 192) bs[t] = bias[t];
  __syncthreads();
  const int wid=t>>6, lane=t&63;
  const int tok0 = (blockIdx.x*4 + wid)*4;
  float x[4];
  #pragma unroll
  for (int c=0;c<4;c++) x[c] = bfu2f(X[(tok0+c)*64 + lane]);
  float acc[4][3];
  #pragma unroll
  for (int c=0;c<4;c++)
    #pragma unroll
    for (int m=0;m<3;m++) acc[c][m] = bs[m*64 + lane];
  for (int k=0;k<64;k++){
    float wv[3];
    #pragma unroll
    for (int m=0;m<3;m++) wv[m] = WT[k*193 + m*64 + lane];
    #pragma unroll
    for (int c=0;c<4;c++){
      float xk = __shfl(x[c], k);
      #pragma unroll
      for (int m=0;m<3;m++) acc[c][m] += xk*wv[m];
    }
  }
  const float qs = 0.17677669529663688f;  // 1/sqrt(32)
  #pragma unroll
  for (int c=0;c<4;c++){
    int tok = tok0+c;
    float vq = acc[c][0]*qs, vk = acc[c][1], vv = acc[c][2];
    int b = tok >> 11, r = tok & 2047;
    u16* row = (MODE==0) ? (dqk0 + (size_t)tok*128) : qk_rowp_w(dqk_r15, dqk_ws, b, r);
    row[lane]      = f2bu(vq);
    row[64 + lane] = f2bu(vk);
    vg[((size_t)((b*64 + (r>>5))*4 + ((r>>2)&3))*64 + lane)*8
       + ((r>>4)&1)*4 + (r&3)] = f2bu(vv);
  }
}

// ---------------- attention (MFMA) + fused proj+residual+LN ----------------
// One block = ONE 16-query tile; the 4 waves SPLIT THE KEY RANGE (512 keys
// each, kt = wv*8..wv*8+8) for occupancy. Per k-tile, per head:
//   S^T tiles:  D = mfma(K_frag, Q_frag)  -> lane holds S^T[j][q=n]
//   exp in f32, partial denominator accumulates in-register
//   P (bf16) re-packed IN-LANE as the PV A-fragment; V B-frag j-tiled.
// No LDS/barriers in the main loop. Partial O (16 f32/lane) + partial denoms
// are combined across waves in LDS in the epilogue, then proj+residual+LN.
// Grid: 2048 blocks, XCD-chunk-swizzled so each XCD covers exactly 2 batches
// (K/V working set 1.5 MB -> L2-resident per XCD).
template<int MODE>
__global__ __launch_bounds__(256) void k_attn_ln(const u16* __restrict__ PQK,
    const u16* __restrict__ QKWS, const u16* __restrict__ VG,
    const float* __restrict__ wo, const float* __restrict__ bo,
    const float* __restrict__ g, const float* __restrict__ be,
    u16* __restrict__ h, float* __restrict__ lout){
  __shared__ float OPW[4096];        // [wv][16][64] partial O; later WOT [k][mo]
  __shared__ float ST[16*68];        // [q][d] normalized attn out (padded)
  __shared__ float DEN[4][2][16];    // per-wave partial denominators
  __shared__ float LAC[2][16];       // combined denominators
  __shared__ float CB[192];          // bo | g | be
  // XCD-chunked bijective swizzle: 2048 blocks, 8 XCDs -> 256 each,
  // XCD x covers nid in [x*256, (x+1)*256) -> bz in {2x, 2x+1}.
  const int lin = blockIdx.x;
  const int nid = (lin & 7)*256 + (lin >> 3);
  const int qt = nid & 127, bz = nid >> 7;
  const int t = threadIdx.x;
  const int lane = t & 63, wv = t >> 6;
  const int n = lane & 15, gq = lane >> 4;
  const f32x4 FZ = {0.f, 0.f, 0.f, 0.f};

  // Q fragments: row q = qt*16 + n, d-slots = hh*32 + gq*8 .. +8 (all waves same)
  bf16x8 qf[2];
  {
    const u16* qrow = (MODE==0) ? (PQK + (size_t)(bz*LQ + qt*16 + n)*128)
                                : qk_rowp(PQK, QKWS, bz, qt*16 + n);
    qf[0] = *(const bf16x8*)(qrow + gq*8);
    qf[1] = *(const bf16x8*)(qrow + 32 + gq*8);
  }
  f32x4 o[2][2];
  #pragma unroll
  for (int hh=0; hh<2; hh++)
    #pragma unroll
    for (int db=0; db<2; db++) o[hh][db] = FZ;
  float dacc[2] = {0.f, 0.f};

  #pragma unroll 1
  for (int kt=wv*8; kt<wv*8+8; kt++){
    #pragma unroll
    for (int hh=0; hh<2; hh++){
      // S^T: lane (gq,n) gets S^T[j = kt*64+jb*16+4gq+reg][q = n]
      f32x4 ev[4];
      #pragma unroll
      for (int jb=0; jb<4; jb++){
        const u16* kr = (MODE==0) ? (PQK + (size_t)(bz*LQ + kt*64 + jb*16 + n)*128)
                                  : qk_rowp(PQK, QKWS, bz, kt*64 + jb*16 + n);
        bf16x8 kf = *(const bf16x8*)(kr + 64 + hh*32 + gq*8);
        ev[jb] = __builtin_amdgcn_mfma_f32_16x16x32_bf16(kf, qf[hh], FZ, 0, 0, 0);
      }
      unsigned pk[4][2];
      float ds = 0.f;
      #pragma unroll
      for (int jb=0; jb<4; jb++){
        float e0 = __expf(ev[jb][0]), e1 = __expf(ev[jb][1]);
        float e2 = __expf(ev[jb][2]), e3 = __expf(ev[jb][3]);
        ds += (e0+e1) + (e2+e3);
        pk[jb][0] = (unsigned)f2bu(e0) | ((unsigned)f2bu(e1) << 16);
        pk[jb][1] = (unsigned)f2bu(e2) | ((unsigned)f2bu(e3) << 16);
      }
      dacc[hh] += ds;
      #pragma unroll
      for (int kb=0; kb<2; kb++){
        union { unsigned u[4]; bf16x8 v; } af;    // PV A-frag from own E's
        af.u[0] = pk[2*kb][0];   af.u[1] = pk[2*kb][1];
        af.u[2] = pk[2*kb+1][0]; af.u[3] = pk[2*kb+1][1];
        #pragma unroll
        for (int db=0; db<2; db++){
          const int d = hh*32 + db*16 + n;
          const bf16x8 vf = *(const bf16x8*)(VG +
              ((size_t)((bz*64 + kt*2 + kb)*4 + gq)*64 + d)*8);
          o[hh][db] = __builtin_amdgcn_mfma_f32_16x16x32_bf16(af.v, vf, o[hh][db], 0, 0, 0);
        }
      }
    }
  }
  // per-wave partial denominators (reduce over the 4 gq groups)
  #pragma unroll
  for (int hh=0; hh<2; hh++){
    float s = dacc[hh];
    s += __shfl_xor(s, 16);
    s += __shfl_xor(s, 32);
    if (gq == 0) DEN[wv][hh][n] = s;
  }
  // per-wave partial O -> LDS; lane holds O[q=gq*4+r][d=hh*32+db*16+n]
  #pragma unroll
  for (int hh=0; hh<2; hh++)
    #pragma unroll
    for (int db=0; db<2; db++)
      #pragma unroll
      for (int r=0; r<4; r++)
        OPW[wv*1024 + (gq*4+r)*64 + hh*32 + db*16 + n] = o[hh][db][r];
  __syncthreads();
  if (t < 32){
    int hh = t >> 4, nn = t & 15;
    float s = DEN[0][hh][nn] + DEN[1][hh][nn] + DEN[2][hh][nn] + DEN[3][hh][nn];
    LAC[hh][nn] = s;
    if (lout) lout[(size_t)(bz*2 + hh)*LQ + qt*16 + nn] = s;
  }
  __syncthreads();
  // combine partial O across waves, normalize -> ST
  for (int e=t; e<1024; e+=256){
    int q = e >> 6, d = e & 63;
    float s = OPW[e] + OPW[1024+e] + OPW[2048+e] + OPW[3072+e];
    ST[q*68 + d] = s / LAC[d>>5][q];
  }
  __syncthreads();                   // OPW dead; reuse as WOT
  float* WOT = OPW;
  for (int e2=t; e2<4096; e2+=256){ int k=e2>>6, mo=e2&63; WOT[e2] = wo[mo*64+k]; }
  if (t < 64)       CB[t] = bo[t];
  else if (t < 128) CB[t] = g[t-64];
  else if (t < 192) CB[t] = be[t-128];
  __syncthreads();
  // proj + residual + LN (4 tokens per wave)
  for (int r=0; r<4; r++){
    int tl = wv*4 + r;
    size_t gtok = (size_t)(bz*LQ + qt*16 + tl);
    float acc = CB[lane];
    for (int k=0; k<64; k++) acc += ST[tl*68 + k] * WOT[k*64 + lane];
    float rr = acc + bfu2f(h[gtok*64 + lane]);
    float s = rr;
    #pragma unroll
    for (int ofs=32; ofs; ofs>>=1) s += __shfl_xor(s, ofs);
    float mean = s * (1.f/64.f);
    float dv = rr - mean;
    float vs = dv*dv;
    #pragma unroll
    for (int ofs=32; ofs; ofs>>=1) vs += __shfl_xor(vs, ofs);
    float rstd = 1.f/sqrtf(vs*(1.f/64.f) + 1e-5f);
    h[gtok*64 + lane] = f2bu(dv*rstd*CB[64+lane] + CB[128+lane]);
  }
}

// ---------------- fused FFN + residual + LN ----------------
__global__ __launch_bounds__(256) void k_ffn(u16* __restrict__ h,
    const float* __restrict__ w1, const float* __restrict__ b1,
    const float* __restrict__ w2, const float* __restrict__ b2,
    const float* __restrict__ g, const float* __restrict__ be){
  __shared__ u16 W1u[64*128];
  __shared__ u16 W2u[128*64];
  __shared__ float B1[128], B2[64], G[64], Bb[64];
  const int t = threadIdx.x;
  for (int e=t; e<8192; e+=256){ int k=e>>7, mo=e&127; W1u[e] = f2bu(w1[mo*64+k]); }
  for (int e=t; e<8192; e+=256){ int k=e>>6, mo=e&63;  W2u[e] = f2bu(w2[mo*128+k]); }
  if (t < 128) B1[t] = b1[t];
  if (t < 64){ B2[t] = b2[t]; G[t] = g[t]; Bb[t] = be[t]; }
  __syncthreads();
  const int wid = t >> 6, lane = t & 63;
  const int tok0 = (blockIdx.x*4 + wid)*4;
  float x[4];
  #pragma unroll
  for (int c=0;c<4;c++) x[c] = bfu2f(h[(tok0+c)*64 + lane]);
  #pragma unroll
  for (int c=0;c<4;c++){
    float a = B1[lane], b = B1[64+lane];
    for (int k=0;k<64;k++){
      float xk = __shfl(x[c], k);
      a += xk * bfu2f(W1u[k*128 + lane]);
      b += xk * bfu2f(W1u[k*128 + 64 + lane]);
    }
    a = fmaxf(a, 0.f); b = fmaxf(b, 0.f);
    float acc = B2[lane];
    for (int k=0;k<64;k++) acc += __shfl(a,k) * bfu2f(W2u[k*64 + lane]);
    for (int k=0;k<64;k++) acc += __shfl(b,k) * bfu2f(W2u[(64+k)*64 + lane]);
    float rr = acc + x[c];
    float s = rr;
    #pragma unroll
    for (int o=32;o;o>>=1) s += __shfl_xor(s,o);
    float mean = s * (1.f/64.f);
    float dv = rr - mean;
    float vs = dv*dv;
    #pragma unroll
    for (int o=32;o;o>>=1) vs += __shfl_xor(vs,o);
    float rstd = 1.f/sqrtf(vs*(1.f/64.f) + 1e-5f);
    h[(tok0+c)*64 + lane] = f2bu(dv*rstd*G[lane] + Bb[lane]);
  }
}

// ---------------- importance (MFMA): recompute scores, column-sum ----------------
// mfma(Q_frag, K_frag): lane (gq,n) reg r holds S[q = wv*16+4gq+r][j = jb*16+n]
// -> 4 in-lane adds + shfl_xor(16,32) = column sum over the wave's 16 q rows.
__global__ __launch_bounds__(256) void k_imp(const u16* __restrict__ qk_r15,
    const u16* __restrict__ qk_ws, const float* __restrict__ l2,
    float* __restrict__ imp){
  __shared__ float IMPS[2048];
  __shared__ float INVL[128];
  const int t = threadIdx.x;
  const int qt = blockIdx.x, bz = blockIdx.y;
  const int lane = t & 63, wv = t >> 6;
  const int n = lane & 15, gq = lane >> 4;
  const f32x4 FZ = {0.f, 0.f, 0.f, 0.f};
  if (t < 128) INVL[t] = 1.f / l2[(size_t)(bz*2 + (t>>6))*LQ + qt*64 + (t&63)];
  for (int e=t; e<2048; e+=256) IMPS[e] = 0.f;
  bf16x8 qf0, qf1;
  {
    const u16* qrow = qk_rowp(qk_r15, qk_ws, bz, qt*64 + wv*16 + n);
    qf0 = *(const bf16x8*)(qrow + gq*8);
    qf1 = *(const bf16x8*)(qrow + 32 + gq*8);
  }
  __syncthreads();
  float iv0[4], iv1[4];
  #pragma unroll
  for (int r=0;r<4;r++){
    iv0[r] = INVL[wv*16 + gq*4 + r];
    iv1[r] = INVL[64 + wv*16 + gq*4 + r];
  }
  for (int kt=0; kt<32; kt++){
    #pragma unroll
    for (int jb=0; jb<4; jb++){
      const u16* kr = qk_rowp(qk_r15, qk_ws, bz, kt*64 + jb*16 + n);
      bf16x8 kf0 = *(const bf16x8*)(kr + 64 + gq*8);
      bf16x8 kf1 = *(const bf16x8*)(kr + 96 + gq*8);
      f32x4 e0 = __builtin_amdgcn_mfma_f32_16x16x32_bf16(qf0, kf0, FZ, 0, 0, 0);
      f32x4 e1 = __builtin_amdgcn_mfma_f32_16x16x32_bf16(qf1, kf1, FZ, 0, 0, 0);
      float cs = 0.f;
      #pragma unroll
      for (int r=0;r<4;r++)
        cs += 0.5f*(__expf(e0[r])*iv0[r] + __expf(e1[r])*iv1[r]);
      cs += __shfl_xor(cs, 16);
      cs += __shfl_xor(cs, 32);
      if (gq == 0) atomicAdd(&IMPS[kt*64 + jb*16 + n], cs);
    }
  }
  __syncthreads();
  for (int e=t; e<2048; e+=256) atomicAdd(&imp[bz*LQ + e], IMPS[e]);
}

// ---------------- pass2 (MFMA): recompute scores, write attn_w FLOAT32 ------
// Grid (256, nb): blockIdx.x = qt*8 + ks; block covers q-tile qt (64 rows) and
// k-tiles kt = ks*4 .. ks*4+4. Per wave: own 16 q rows, all 64 j of the tile.
// S^T from mfma(K_frag, Q_frag); stage per-wave-private STG rows; write
// 256 B-contiguous rows. No barriers in the main loop.
__global__ __launch_bounds__(256) void k_pass2(const u16* __restrict__ qk_r15,
    const u16* __restrict__ qk_ws, const float* __restrict__ l2,
    float* __restrict__ wout, int bz0){
  __shared__ float STG[64*68];       // [q][j] staging, per-wave-private rows
  __shared__ float INVL[128];
  const int t = threadIdx.x;
  const int qt = blockIdx.x >> 3, ks = blockIdx.x & 7;
  const int bz = bz0 + blockIdx.y;
  const int lane = t & 63, wv = t >> 6;
  const int n = lane & 15, gq = lane >> 4;
  const f32x4 FZ = {0.f, 0.f, 0.f, 0.f};
  if (t < 128) INVL[t] = 1.f / l2[(size_t)(bz*2 + (t>>6))*LQ + qt*64 + (t&63)];
  bf16x8 qf0, qf1;
  {
    const u16* qrow = qk_rowp(qk_r15, qk_ws, bz, qt*64 + wv*16 + n);
    qf0 = *(const bf16x8*)(qrow + gq*8);
    qf1 = *(const bf16x8*)(qrow + 32 + gq*8);
  }
  __syncthreads();
  const float iv0 = INVL[wv*16 + n], iv1 = INVL[64 + wv*16 + n];
  for (int kt = ks*4; kt < ks*4 + 4; kt++){
    #pragma unroll
    for (int jb=0; jb<4; jb++){
      const u16* kr = qk_rowp(qk_r15, qk_ws, bz, kt*64 + jb*16 + n);
      bf16x8 kf0 = *(const bf16x8*)(kr + 64 + gq*8);
      bf16x8 kf1 = *(const bf16x8*)(kr + 96 + gq*8);
      f32x4 e0 = __builtin_amdgcn_mfma_f32_16x16x32_bf16(kf0, qf0, FZ, 0, 0, 0);
      f32x4 e1 = __builtin_amdgcn_mfma_f32_16x16x32_bf16(kf1, qf1, FZ, 0, 0, 0);
      // lane (gq,n) reg r: w[q = wv*16+n][j = jb*16+4gq+r]
      float4 w4;
      w4.x = 0.5f*(__expf(e0[0])*iv0 + __expf(e1[0])*iv1);
      w4.y = 0.5f*(__expf(e0[1])*iv0 + __expf(e1[1])*iv1);
      w4.z = 0.5f*(__expf(e0[2])*iv0 + __expf(e1[2])*iv1);
      w4.w = 0.5f*(__expf(e0[3])*iv0 + __expf(e1[3])*iv1);
      *(float4*)(&STG[(wv*16 + n)*68 + jb*16 + 4*gq]) = w4;
    }
    size_t base = 1 + (size_t)bz*LQ*LQ + (size_t)(qt*64)*LQ + (size_t)kt*64;
    for (int r=0; r<16; r++){
      int q = wv*16 + r;
      wout[base + (size_t)q*LQ + lane] = STG[q*68 + lane];
    }
  }
}

// ---------------- top-k (M=8, ties -> lowest index) — LDS serial ----------------
__global__ __launch_bounds__(64) void k_topk(const float* __restrict__ imp,
                                             int* __restrict__ topki){
  __shared__ float v[2048];
  __shared__ float bv[64];
  __shared__ int   bi[64];
  __shared__ int   chosen;
  const int b = blockIdx.x, lane = threadIdx.x;
  for (int i=lane; i<2048; i+=64) v[i] = imp[b*2048 + i];
  __syncthreads();
  for (int m=0; m<8; m++){
    float best = -1e30f; int besti = 1<<30;
    for (int i=lane; i<2048; i+=64)
      if (v[i] > best || (v[i] == best && i < besti)){ best = v[i]; besti = i; }
    bv[lane] = best; bi[lane] = besti;
    __syncthreads();
    if (lane == 0){
      float B = bv[0]; int I = bi[0];
      for (int i2=1; i2<64; i2++)
        if (bv[i2] > B || (bv[i2] == B && bi[i2] < I)){ B = bv[i2]; I = bi[i2]; }
      topki[b*8 + m] = (I < 0) ? 0 : (I > 2047 ? 2047 : I);
      chosen = (I < 0) ? 0 : (I > 2047 ? 2047 : I);
    }
    __syncthreads();
    if (lane == 0) v[chosen] = -1e30f;
    __syncthreads();
  }
}

// ---------------- memory reader + loss — one block per batch, wave-parallel ----
__global__ __launch_bounds__(64) void k_loss(const u16* __restrict__ h,
    const int* __restrict__ topki, const int* __restrict__ query, const int* __restrict__ target,
    const float* __restrict__ qemb, const float* __restrict__ rq_w, const float* __restrict__ rq_b,
    const float* __restrict__ ro_w, const float* __restrict__ ro_b, float* __restrict__ loss_out){
  const int b = blockIdx.x, lane = threadIdx.x;
  float mv[8];
  #pragma unroll
  for (int m=0; m<8; m++){
    int idx = topki[b*8+m] & 2047;
    mv[m] = bfu2f(h[(size_t)(b*LQ + idx)*64 + lane]);
  }
  float qh = qemb[((query[b]&63)<<6) + lane];
  float qd = rq_b[lane];
  for (int k=0;k<64;k++) qd += __shfl(qh,k) * rq_w[lane*64 + k];
  float sc[8];
  #pragma unroll
  for (int m=0;m<8;m++){
    float p = qd * mv[m];
    #pragma unroll
    for (int o=32;o;o>>=1) p += __shfl_xor(p,o);
    sc[m] = p * 0.125f;   // 1/sqrt(64)
  }
  float mx = sc[0];
  #pragma unroll
  for (int m=1;m<8;m++) mx = fmaxf(mx, sc[m]);
  float den = 0.f, rd = 0.f;
  #pragma unroll
  for (int m=0;m<8;m++){ float w = __expf(sc[m]-mx); den += w; rd += w*mv[m]; }
  rd /= den;
  float lg = ro_b[lane];
  for (int d=0;d<64;d++) lg += __shfl(rd,d) * ro_w[lane*64 + d];
  float lmx = lg;
  #pragma unroll
  for (int o=32;o;o>>=1) lmx = fmaxf(lmx, __shfl_xor(lmx,o));
  float ex = __expf(lg - lmx), es = ex;
  #pragma unroll
  for (int o=32;o;o>>=1) es += __shfl_xor(es,o);
  float lt = __shfl(lg, target[b]&63);
  if (lane == 0) atomicAdd(loss_out, -(lt - lmx - logf(es)) * (1.f/16.f));
}

// ---------------- final: f32 loss -> out_f[0] (runs LAST) ----------------
__global__ void k_store_loss(const float* __restrict__ ls, float* __restrict__ out){
  out[0] = ls[0];
}

// ---------------- launch ----------------
extern "C" void kernel_launch(void* const* d_in, const int* in_sizes, int n_in,
                              void* d_out, int out_size, void* d_ws, size_t ws_size,
                              hipStream_t stream){
  const int*   seq    = (const int*)  d_in[0];
  const int*   query  = (const int*)  d_in[1];
  const int*   target = (const int*)  d_in[2];
  const float* embed  = (const float*)d_in[3];
  const float* a1_wi  = (const float*)d_in[4];
  const float* a1_bi  = (const float*)d_in[5];
  const float* a1_wo  = (const float*)d_in[6];
  const float* a1_bo  = (const float*)d_in[7];
  const float* ff1_w1 = (const float*)d_in[8];
  const float* ff1_b1 = (const float*)d_in[9];
  const float* ff1_w2 = (const float*)d_in[10];
  const float* ff1_b2 = (const float*)d_in[11];
  const float* ln1a_g = (const float*)d_in[12];
  const float* ln1a_b = (const float*)d_in[13];
  const float* ln1b_g = (const float*)d_in[14];
  const float* ln1b_b = (const float*)d_in[15];
  const float* a2_wi  = (const float*)d_in[16];
  const float* a2_bi  = (const float*)d_in[17];
  const float* a2_wo  = (const float*)d_in[18];
  const float* a2_bo  = (const float*)d_in[19];
  const float* ff2_w1 = (const float*)d_in[20];
  const float* ff2_b1 = (const float*)d_in[21];
  const float* ff2_w2 = (const float*)d_in[22];
  const float* ff2_b2 = (const float*)d_in[23];
  const float* ln2a_g = (const float*)d_in[24];
  const float* ln2a_b = (const float*)d_in[25];
  const float* ln2b_g = (const float*)d_in[26];
  const float* ln2b_b = (const float*)d_in[27];
  const float* rq_w   = (const float*)d_in[28];
  const float* rq_b   = (const float*)d_in[29];
  const float* ro_w   = (const float*)d_in[30];
  const float* ro_b   = (const float*)d_in[31];
  const float* qemb   = (const float*)d_in[32];

  // d_ws (918,020 B)
  char* wsb      = (char*)d_ws;
  u16*  qk_ws    = (u16*)(wsb);                // 524,288 B (batch 15 [Qs|K])
  float* ws_imp  = (float*)(wsb + 524288);     // 131,072 B
  float* ws_l    = (float*)(wsb + 655360);     // 262,144 B
  int*  ws_top   = (int*)(wsb + 917504);       // 512 B
  float* ws_loss = (float*)(wsb + 918016);     // 4 B

  // d_out (FLOAT32, 268,435,460 B) + scratch parking
  float* out_f  = (float*)d_out;
  u16* h16     = (u16*)((char*)d_out + 64);          // 4 MB bf16, region 0
  u16* qk1     = (u16*)((char*)d_out + 4194368);     // 8 MB layer-1 [Qs|K]
  u16* vg1     = (u16*)((char*)d_out + 12582976);    // 4 MB layer-1 V (j-tiled)
  u16* vg2     = (u16*)((char*)d_out + 4194368);     // 4 MB layer-2 V (j-tiled)
  u16* qk_r15  = (u16*)((char*)d_out + 251658304);   // 7.7 MB, region 15

  k_embed<<<8192,256,0,stream>>>(seq, embed, h16);
  k_zero<<<128,256,0,stream>>>(ws_imp, ws_loss);
  // layer 1
  k_qkv<0><<<2048,256,0,stream>>>(h16, a1_wi, a1_bi, qk1, nullptr, nullptr, vg1);
  k_attn_ln<0><<<2048,256,0,stream>>>(qk1, nullptr, vg1,
                                      a1_wo, a1_bo, ln1a_g, ln1a_b, h16, nullptr);
  k_ffn<<<2048,256,0,stream>>>(h16, ff1_w1, ff1_b1, ff1_w2, ff1_b2, ln1b_g, ln1b_b);
  // layer 2
  k_qkv<1><<<2048,256,0,stream>>>(h16, a2_wi, a2_bi, nullptr, qk_r15, qk_ws, vg2);
  k_attn_ln<1><<<2048,256,0,stream>>>(qk_r15, qk_ws, vg2,
                                      a2_wo, a2_bo, ln2a_g, ln2a_b, h16, ws_l);
  k_ffn<<<2048,256,0,stream>>>(h16, ff2_w1, ff2_b1, ff2_w2, ff2_b2, ln2b_g, ln2b_b);
  // importance -> topk -> loss (loss to d_ws; h16 still alive)
  k_imp<<<dim3(32,16),256,0,stream>>>(qk_r15, qk_ws, ws_l, ws_imp);
  k_topk<<<16,64,0,stream>>>(ws_imp, ws_top);
  k_loss<<<16,64,0,stream>>>(h16, ws_top, query, target, qemb, rq_w, rq_b, ro_w, ro_b, ws_loss);
  // attn_w FLOAT32 (destroys d_out scratch): wave1 b0-14, wave2 b15
  k_pass2<<<dim3(256,15),256,0,stream>>>(qk_r15, qk_ws, ws_l, out_f, 0);
  k_pass2<<<dim3(256,1),256,0,stream>>>(qk_r15, qk_ws, ws_l, out_f, 15);
  // loss stored LAST
  k_store_loss<<<1,1,0,stream>>>(ws_loss, out_f);
}

// Round 4
// 862.535 us; speedup vs baseline: 3.4297x; 1.2321x over previous
//
#include <hip/hip_runtime.h>
#include <hip/hip_bf16.h>

// RecallModel: B=16, L=2048, H=64, NH=2, HD=32, M=8, V=64.
// Inputs: ints int32; floats FP32. OUTPUTS FLOAT32 (reference dtype!):
//   out_f[0] = loss, out_f[1..1+16*2048*2048) = attn_w (B,L,L). 268,435,460 B.
//
// d_ws usage: 918,020 bytes:
//   qk15 @0       524,288 B  bf16 [Qs|K] batch 15 (layer 2)
//   imp  @524288  131,072 B  f32 imp[16][2048]
//   l2   @655360  262,144 B  f32 sum-of-exp
//   topk @917504      512 B
//   loss @918016        4 B  f32
// d_out doubles as scratch (dead-before-overwrite). attn batch-b region =
// bytes [4 + b*16777216, 4 + (b+1)*16777216).
//   qk1    @ byte 4194368    8 MB bf16 layer-1 [Qs|K] rows s128 (dies at attn1)
//   vg1    @ byte 12582976   4 MB bf16 layer-1 V, j-tiled (dies at attn1;
//                                 60 B spill into region 1 is dead too)
//   vg2    @ byte 4194368    4 MB bf16 layer-2 V, j-tiled (dies at attn2)
//   qk0-14 @ byte 251658304  7.7 MB (region-15 head; dies at pass2 wave2)
//   h      @ byte 259522624  4 MB bf16 (region-15 TAIL, after qk_r15; survives
//                                 pass2 wave1; dies at pass2 wave2)
// NEW ORDER: pass2 wave1 (bz0-14, writes regions 0-14, fused importance) ->
// k_imp15 (bz15 only, reads d_ws) -> topk -> loss (h16 alive in region-15
// tail) -> pass2 wave2 (bz15, overwrites region 15) -> store loss.
//
// V j-tiled layout (per batch): element (j,d) at
//   ((( (j>>5)*4 + ((j>>2)&3) )*64 + d)*8 + ((j>>4)&1)*4 + (j&3)
// so the PV B-fragment (lane g: j in {J0+4g..+3} u {J0+16+4g..+3}) is ONE
// contiguous 16 B load per lane (coalesced 256 B per 16-lane group).

typedef unsigned short u16;
#define LQ 2048
#define BBATCH 16
#define QKB 262144   // u16 elements per batch of packed [Qs|K] (2048*128)

typedef __attribute__((ext_vector_type(8))) short bf16x8;
typedef __attribute__((ext_vector_type(4))) float f32x4;

__device__ __forceinline__ float bfu2f(u16 x){ return __uint_as_float(((unsigned)x) << 16); }
__device__ __forceinline__ u16 f2bu(float f){ return __bfloat16_as_ushort(__float2bfloat16(f)); }

__device__ __forceinline__ const u16* qk_rowp(const u16* qk_r15, const u16* qk_ws,
                                              int bz, int row){
  const u16* base = (bz < 15) ? (qk_r15 + (size_t)bz*QKB) : qk_ws;
  return base + (size_t)row*128;
}
__device__ __forceinline__ u16* qk_rowp_w(u16* qk_r15, u16* qk_ws, int bz, int row){
  u16* base = (bz < 15) ? (qk_r15 + (size_t)bz*QKB) : qk_ws;
  return base + (size_t)row*128;
}

// ---------------- embed ----------------
__global__ __launch_bounds__(256) void k_embed(const int* __restrict__ seq,
                                               const float* __restrict__ emb,
                                               u16* __restrict__ h){
  int i = blockIdx.x*256 + threadIdx.x;      // 32768*64
  int tok = i >> 6, d = i & 63;
  int v = seq[tok] & 63;
  h[i] = f2bu(emb[(v << 6) + d]);
}

__global__ __launch_bounds__(256) void k_zero(float* __restrict__ p, float* __restrict__ q){
  int i = blockIdx.x*256 + threadIdx.x;
  p[i] = 0.f;
  if (i == 0) q[0] = 0.f;
}

// ---------------- qkv projection ----------------
// Writes [Qs|K] rows (stride 128 u16) + V in j-tiled layout (see header).
template<int MODE>
__global__ __launch_bounds__(256) void k_qkv(const u16* __restrict__ X,
                                             const float* __restrict__ W,
                                             const float* __restrict__ bias,
                                             u16* __restrict__ dqk0,
                                             u16* __restrict__ dqk_r15,
                                             u16* __restrict__ dqk_ws,
                                             u16* __restrict__ vg){
  __shared__ float WT[64*193];   // [k][mo]
  __shared__ float bs[192];
  const int t = threadIdx.x;
  for (int e=t; e<192*64; e+=256){ int mo=e>>6, k=e&63; WT[k*193+mo] = W[e]; }
  if (t < 192) bs[t] = bias[t];
  __syncthreads();
  const int wid=t>>6, lane=t&63;
  const int tok0 = (blockIdx.x*4 + wid)*4;
  float x[4];
  #pragma unroll
  for (int c=0;c<4;c++) x[c] = bfu2f(X[(tok0+c)*64 + lane]);
  float acc[4][3];
  #pragma unroll
  for (int c=0;c<4;c++)
    #pragma unroll
    for (int m=0;m<3;m++) acc[c][m] = bs[m*64 + lane];
  for (int k=0;k<64;k++){
    float wv[3];
    #pragma unroll
    for (int m=0;m<3;m++) wv[m] = WT[k*193 + m*64 + lane];
    #pragma unroll
    for (int c=0;c<4;c++){
      float xk = __shfl(x[c], k);
      #pragma unroll
      for (int m=0;m<3;m++) acc[c][m] += xk*wv[m];
    }
  }
  const float qs = 0.17677669529663688f;  // 1/sqrt(32)
  #pragma unroll
  for (int c=0;c<4;c++){
    int tok = tok0+c;
    float vq = acc[c][0]*qs, vk = acc[c][1], vv = acc[c][2];
    int b = tok >> 11, r = tok & 2047;
    u16* row = (MODE==0) ? (dqk0 + (size_t)tok*128) : qk_rowp_w(dqk_r15, dqk_ws, b, r);
    row[lane]      = f2bu(vq);
    row[64 + lane] = f2bu(vk);
    vg[((size_t)((b*64 + (r>>5))*4 + ((r>>2)&3))*64 + lane)*8
       + ((r>>4)&1)*4 + (r&3)] = f2bu(vv);
  }
}

// ---------------- attention (MFMA) + fused proj+residual+LN ----------------
// One block = ONE 16-query tile; the 4 waves SPLIT THE KEY RANGE (512 keys
// each, kt = wv*8..wv*8+8) for occupancy. Per k-tile, per head:
//   S^T tiles:  D = mfma(K_frag, Q_frag)  -> lane holds S^T[j][q=n]
//   exp in f32, partial denominator accumulates in-register
//   P (bf16) re-packed IN-LANE as the PV A-fragment; V B-frag j-tiled.
// No LDS/barriers in the main loop. Partial O (16 f32/lane) + partial denoms
// are combined across waves in LDS in the epilogue, then proj+residual+LN.
// Grid: 2048 blocks, XCD-chunk-swizzled so each XCD covers exactly 2 batches
// (K/V working set ~1 MB -> L2-resident per XCD).
template<int MODE>
__global__ __launch_bounds__(256) void k_attn_ln(const u16* __restrict__ PQK,
    const u16* __restrict__ QKWS, const u16* __restrict__ VG,
    const float* __restrict__ wo, const float* __restrict__ bo,
    const float* __restrict__ g, const float* __restrict__ be,
    u16* __restrict__ h, float* __restrict__ lout){
  __shared__ float OPW[4096];        // [wv][16][64] partial O; later WOT [k][mo]
  __shared__ float ST[16*68];        // [q][d] normalized attn out (padded)
  __shared__ float DEN[4][2][16];    // per-wave partial denominators
  __shared__ float LAC[2][16];       // combined denominators
  __shared__ float CB[192];          // bo | g | be
  // XCD-chunked bijective swizzle: 2048 blocks, 8 XCDs -> 256 each,
  // XCD x covers nid in [x*256, (x+1)*256) -> bz in {2x, 2x+1}.
  const int lin = blockIdx.x;
  const int nid = (lin & 7)*256 + (lin >> 3);
  const int qt = nid & 127, bz = nid >> 7;
  const int t = threadIdx.x;
  const int lane = t & 63, wv = t >> 6;
  const int n = lane & 15, gq = lane >> 4;
  const f32x4 FZ = {0.f, 0.f, 0.f, 0.f};

  // Q fragments: row q = qt*16 + n, d-slots = hh*32 + gq*8 .. +8 (all waves same)
  bf16x8 qf[2];
  {
    const u16* qrow = (MODE==0) ? (PQK + (size_t)(bz*LQ + qt*16 + n)*128)
                                : qk_rowp(PQK, QKWS, bz, qt*16 + n);
    qf[0] = *(const bf16x8*)(qrow + gq*8);
    qf[1] = *(const bf16x8*)(qrow + 32 + gq*8);
  }
  f32x4 o[2][2];
  #pragma unroll
  for (int hh=0; hh<2; hh++)
    #pragma unroll
    for (int db=0; db<2; db++) o[hh][db] = FZ;
  float dacc[2] = {0.f, 0.f};

  #pragma unroll 1
  for (int kt=wv*8; kt<wv*8+8; kt++){
    #pragma unroll
    for (int hh=0; hh<2; hh++){
      // S^T: lane (gq,n) gets S^T[j = kt*64+jb*16+4gq+reg][q = n]
      f32x4 ev[4];
      #pragma unroll
      for (int jb=0; jb<4; jb++){
        const u16* kr = (MODE==0) ? (PQK + (size_t)(bz*LQ + kt*64 + jb*16 + n)*128)
                                  : qk_rowp(PQK, QKWS, bz, kt*64 + jb*16 + n);
        bf16x8 kf = *(const bf16x8*)(kr + 64 + hh*32 + gq*8);
        ev[jb] = __builtin_amdgcn_mfma_f32_16x16x32_bf16(kf, qf[hh], FZ, 0, 0, 0);
      }
      unsigned pk[4][2];
      float ds = 0.f;
      #pragma unroll
      for (int jb=0; jb<4; jb++){
        float e0 = __expf(ev[jb][0]), e1 = __expf(ev[jb][1]);
        float e2 = __expf(ev[jb][2]), e3 = __expf(ev[jb][3]);
        ds += (e0+e1) + (e2+e3);
        pk[jb][0] = (unsigned)f2bu(e0) | ((unsigned)f2bu(e1) << 16);
        pk[jb][1] = (unsigned)f2bu(e2) | ((unsigned)f2bu(e3) << 16);
      }
      dacc[hh] += ds;
      #pragma unroll
      for (int kb=0; kb<2; kb++){
        union { unsigned u[4]; bf16x8 v; } af;    // PV A-frag from own E's
        af.u[0] = pk[2*kb][0];   af.u[1] = pk[2*kb][1];
        af.u[2] = pk[2*kb+1][0]; af.u[3] = pk[2*kb+1][1];
        #pragma unroll
        for (int db=0; db<2; db++){
          const int d = hh*32 + db*16 + n;
          const bf16x8 vf = *(const bf16x8*)(VG +
              ((size_t)((bz*64 + kt*2 + kb)*4 + gq)*64 + d)*8);
          o[hh][db] = __builtin_amdgcn_mfma_f32_16x16x32_bf16(af.v, vf, o[hh][db], 0, 0, 0);
        }
      }
    }
  }
  // per-wave partial denominators (reduce over the 4 gq groups)
  #pragma unroll
  for (int hh=0; hh<2; hh++){
    float s = dacc[hh];
    s += __shfl_xor(s, 16);
    s += __shfl_xor(s, 32);
    if (gq == 0) DEN[wv][hh][n] = s;
  }
  // per-wave partial O -> LDS; lane holds O[q=gq*4+r][d=hh*32+db*16+n]
  #pragma unroll
  for (int hh=0; hh<2; hh++)
    #pragma unroll
    for (int db=0; db<2; db++)
      #pragma unroll
      for (int r=0; r<4; r++)
        OPW[wv*1024 + (gq*4+r)*64 + hh*32 + db*16 + n] = o[hh][db][r];
  __syncthreads();
  if (t < 32){
    int hh = t >> 4, nn = t & 15;
    float s = DEN[0][hh][nn] + DEN[1][hh][nn] + DEN[2][hh][nn] + DEN[3][hh][nn];
    LAC[hh][nn] = s;
    if (lout) lout[(size_t)(bz*2 + hh)*LQ + qt*16 + nn] = s;
  }
  __syncthreads();
  // combine partial O across waves, normalize -> ST
  for (int e=t; e<1024; e+=256){
    int q = e >> 6, d = e & 63;
    float s = OPW[e] + OPW[1024+e] + OPW[2048+e] + OPW[3072+e];
    ST[q*68 + d] = s / LAC[d>>5][q];
  }
  __syncthreads();                   // OPW dead; reuse as WOT
  float* WOT = OPW;
  for (int e2=t; e2<4096; e2+=256){ int k=e2>>6, mo=e2&63; WOT[e2] = wo[mo*64+k]; }
  if (t < 64)       CB[t] = bo[t];
  else if (t < 128) CB[t] = g[t-64];
  else if (t < 192) CB[t] = be[t-128];
  __syncthreads();
  // proj + residual + LN (4 tokens per wave)
  for (int r=0; r<4; r++){
    int tl = wv*4 + r;
    size_t gtok = (size_t)(bz*LQ + qt*16 + tl);
    float acc = CB[lane];
    for (int k=0; k<64; k++) acc += ST[tl*68 + k] * WOT[k*64 + lane];
    float rr = acc + bfu2f(h[gtok*64 + lane]);
    float s = rr;
    #pragma unroll
    for (int ofs=32; ofs; ofs>>=1) s += __shfl_xor(s, ofs);
    float mean = s * (1.f/64.f);
    float dv = rr - mean;
    float vs = dv*dv;
    #pragma unroll
    for (int ofs=32; ofs; ofs>>=1) vs += __shfl_xor(vs, ofs);
    float rstd = 1.f/sqrtf(vs*(1.f/64.f) + 1e-5f);
    h[gtok*64 + lane] = f2bu(dv*rstd*CB[64+lane] + CB[128+lane]);
  }
}

// ---------------- fused FFN + residual + LN (MFMA) ----------------
// Swapped-operand trick twice so token stays in the lane index end-to-end:
//   H1^T = mfma(W1_frag, X_frag): lane (gq,n) holds H1[tok n][ct*16+4gq+r]
//   y    = mfma(W2_frag, H1_frag) over k=192: 4 real W2 k-blocks (map kappa)
//          + 2 IDENTITY k-blocks whose B-frag is the X fragment (residual!).
// A and B use the same k-slot map per block -> contraction exact.
// W1/W2 staged in LDS bf16, XOR-swizzled ((row&7)<<3 on u16 index) to kill
// the stride-128B 16-way bank conflict. LN per token: o spread over gq axis
// -> 2 shfl_xor. Output staged in LDS (swizzled), flushed coalesced.
__global__ __launch_bounds__(256) void k_ffn(u16* __restrict__ h,
    const float* __restrict__ w1, const float* __restrict__ b1,
    const float* __restrict__ w2, const float* __restrict__ b2,
    const float* __restrict__ g, const float* __restrict__ be){
  __shared__ u16 W1L[128*64];      // [h1row][64 d] swizzled
  __shared__ u16 W2L[64*192];      // [o][6 kblk * 32] swizzled (4 W2 + 2 I)
  __shared__ u16 YL[64*64];        // y bf16 staging (swizzled by row)
  __shared__ float B1[128], B2F[64], G[64], Bb[64];
  const int t = threadIdx.x;
  for (int e=t; e<8192; e+=256){
    int row = e>>6, col = e&63;
    W1L[row*64 + (col ^ ((row&7)<<3))] = f2bu(w1[e]);
  }
  for (int e=t; e<12288; e+=256){
    int o = e/192, rem = e%192, u = rem>>5, gs = rem&31, gq2 = gs>>3, s = gs&7;
    float val;
    if (u < 4) val = w2[o*128 + u*32 + ((s>>2)<<4) + gq2*4 + (s&3)];
    else { int d = ((u-4)<<5) + gq2*8 + s; val = (d==o) ? 1.f : 0.f; }
    W2L[o*192 + ((u*32+gs) ^ ((o&7)<<3))] = f2bu(val);
  }
  if (t < 128) B1[t] = b1[t];
  if (t < 64){ B2F[t] = b2[t]; G[t] = g[t]; Bb[t] = be[t]; }
  __syncthreads();
  const int lane = t & 63, wv = t >> 6;
  const int n = lane & 15, gq = lane >> 4;
  const int tok0 = blockIdx.x*64 + wv*16;
  // X fragments: lane (gq,n): token n, d-slots v*32+gq*8..+8
  bf16x8 xf[2];
  xf[0] = *(const bf16x8*)(h + (size_t)(tok0+n)*64 + gq*8);
  xf[1] = *(const bf16x8*)(h + (size_t)(tok0+n)*64 + 32 + gq*8);
  // GEMM1: acc1[ct][r] = H1[tok n][ct*16+4gq+r] (pre-relu)
  f32x4 acc1[8];
  #pragma unroll
  for (int ct=0; ct<8; ct++){
    f32x4 c;
    #pragma unroll
    for (int r=0;r<4;r++) c[r] = B1[ct*16 + gq*4 + r];
    bf16x8 w1f0 = *(const bf16x8*)(W1L + (ct*16+n)*64 + ((gq*8) ^ ((n&7)<<3)));
    bf16x8 w1f1 = *(const bf16x8*)(W1L + (ct*16+n)*64 + ((32+gq*8) ^ ((n&7)<<3)));
    c = __builtin_amdgcn_mfma_f32_16x16x32_bf16(w1f0, xf[0], c, 0, 0, 0);
    c = __builtin_amdgcn_mfma_f32_16x16x32_bf16(w1f1, xf[1], c, 0, 0, 0);
    acc1[ct] = c;
  }
  // GEMM2 (+residual via identity blocks): acc2[ot][r] = y[tok n][ot*16+4gq+r]
  f32x4 acc2[4];
  #pragma unroll
  for (int ot=0; ot<4; ot++)
    #pragma unroll
    for (int r=0;r<4;r++) acc2[ot][r] = B2F[ot*16 + gq*4 + r];
  #pragma unroll
  for (int u=0; u<6; u++){
    union { unsigned uu[4]; bf16x8 v; } bfr;
    if (u < 4){
      #pragma unroll
      for (int i=0;i<4;i++){
        int ct = u*2 + (i>>1);
        float a = fmaxf(acc1[ct][(2*i)&3], 0.f);
        float b = fmaxf(acc1[ct][(2*i+1)&3], 0.f);
        bfr.uu[i] = (unsigned)f2bu(a) | ((unsigned)f2bu(b) << 16);
      }
    } else {
      bfr.v = xf[u-4];
    }
    #pragma unroll
    for (int ot=0; ot<4; ot++){
      bf16x8 w2f = *(const bf16x8*)(W2L + (ot*16+n)*192 + ((u*32+gq*8) ^ ((n&7)<<3)));
      acc2[ot] = __builtin_amdgcn_mfma_f32_16x16x32_bf16(w2f, bfr.v, acc2[ot], 0, 0, 0);
    }
  }
  // LayerNorm over o (two-pass); token n's 64 o-values live in 4 gq-lanes x 16
  float s1 = 0.f;
  #pragma unroll
  for (int ot=0;ot<4;ot++)
    #pragma unroll
    for (int r=0;r<4;r++) s1 += acc2[ot][r];
  s1 += __shfl_xor(s1, 16); s1 += __shfl_xor(s1, 32);
  float mean = s1 * (1.f/64.f);
  float s2 = 0.f;
  #pragma unroll
  for (int ot=0;ot<4;ot++)
    #pragma unroll
    for (int r=0;r<4;r++){ float dv = acc2[ot][r]-mean; s2 += dv*dv; }
  s2 += __shfl_xor(s2, 16); s2 += __shfl_xor(s2, 32);
  float rstd = 1.f/sqrtf(s2*(1.f/64.f) + 1e-5f);
  #pragma unroll
  for (int ot=0;ot<4;ot++)
    #pragma unroll
    for (int r=0;r<4;r++){
      int o = ot*16 + gq*4 + r;
      float yv = (acc2[ot][r]-mean)*rstd*G[o] + Bb[o];
      YL[(wv*16+n)*64 + (o ^ ((n&7)<<3))] = f2bu(yv);
    }
  __syncthreads();
  // coalesced flush of this wave's 16 rows (u32 granules, un-swizzle)
  unsigned* h32 = (unsigned*)(h + (size_t)(blockIdx.x)*64*64);
  #pragma unroll
  for (int i=0;i<8;i++){
    int idx = i*64 + lane;           // 0..511 over wave
    int row = wv*16 + (idx>>5), c32 = idx&31;
    unsigned vv = *(const unsigned*)(YL + row*64 + ((c32*2) ^ ((row&7)<<3)));
    h32[row*32 + c32] = vv;
  }
}

// ---------------- importance (MFMA) for ONE batch (bz0+blockIdx.y) ----------
// Kept only for bz=15 (its Q/K live in d_ws; its pass2 wave runs last).
__global__ __launch_bounds__(256) void k_imp(const u16* __restrict__ qk_r15,
    const u16* __restrict__ qk_ws, const float* __restrict__ l2,
    float* __restrict__ imp, int bz0){
  __shared__ float IMPS[2048];
  __shared__ float INVL[128];
  const int t = threadIdx.x;
  const int qt = blockIdx.x, bz = bz0 + blockIdx.y;
  const int lane = t & 63, wv = t >> 6;
  const int n = lane & 15, gq = lane >> 4;
  const f32x4 FZ = {0.f, 0.f, 0.f, 0.f};
  if (t < 128) INVL[t] = 1.f / l2[(size_t)(bz*2 + (t>>6))*LQ + qt*64 + (t&63)];
  for (int e=t; e<2048; e+=256) IMPS[e] = 0.f;
  bf16x8 qf0, qf1;
  {
    const u16* qrow = qk_rowp(qk_r15, qk_ws, bz, qt*64 + wv*16 + n);
    qf0 = *(const bf16x8*)(qrow + gq*8);
    qf1 = *(const bf16x8*)(qrow + 32 + gq*8);
  }
  __syncthreads();
  float iv0[4], iv1[4];
  #pragma unroll
  for (int r=0;r<4;r++){
    iv0[r] = INVL[wv*16 + gq*4 + r];
    iv1[r] = INVL[64 + wv*16 + gq*4 + r];
  }
  for (int kt=0; kt<32; kt++){
    #pragma unroll
    for (int jb=0; jb<4; jb++){
      const u16* kr = qk_rowp(qk_r15, qk_ws, bz, kt*64 + jb*16 + n);
      bf16x8 kf0 = *(const bf16x8*)(kr + 64 + gq*8);
      bf16x8 kf1 = *(const bf16x8*)(kr + 96 + gq*8);
      f32x4 e0 = __builtin_amdgcn_mfma_f32_16x16x32_bf16(qf0, kf0, FZ, 0, 0, 0);
      f32x4 e1 = __builtin_amdgcn_mfma_f32_16x16x32_bf16(qf1, kf1, FZ, 0, 0, 0);
      float cs = 0.f;
      #pragma unroll
      for (int r=0;r<4;r++)
        cs += 0.5f*(__expf(e0[r])*iv0[r] + __expf(e1[r])*iv1[r]);
      cs += __shfl_xor(cs, 16);
      cs += __shfl_xor(cs, 32);
      if (gq == 0) atomicAdd(&IMPS[kt*64 + jb*16 + n], cs);
    }
  }
  __syncthreads();
  for (int e=t; e<2048; e+=256) atomicAdd(&imp[bz*LQ + e], IMPS[e]);
}

// ---------------- pass2 (MFMA): scores -> attn_w FLOAT32 (+fused importance) -
// Grid (256, nb): blockIdx.x = qt*8 + ks; block covers q-tile qt (64 rows) and
// k-tiles kt = ks*4 .. ks*4+4. Per wave: own 16 q rows, all 64 j of the tile.
// S^T from mfma(K_frag, Q_frag); stage per-wave-private STG rows; write
// 256 B-contiguous rows. Column sums accumulate for free in the write loop
// (DOIMP): one atomicAdd per thread per k-tile.
template<int DOIMP>
__global__ __launch_bounds__(256) void k_pass2(const u16* __restrict__ qk_r15,
    const u16* __restrict__ qk_ws, const float* __restrict__ l2,
    float* __restrict__ imp, float* __restrict__ wout, int bz0){
  __shared__ float STG[64*68];       // [q][j] staging, per-wave-private rows
  __shared__ float INVL[128];
  const int t = threadIdx.x;
  const int qt = blockIdx.x >> 3, ks = blockIdx.x & 7;
  const int bz = bz0 + blockIdx.y;
  const int lane = t & 63, wv = t >> 6;
  const int n = lane & 15, gq = lane >> 4;
  const f32x4 FZ = {0.f, 0.f, 0.f, 0.f};
  if (t < 128) INVL[t] = 1.f / l2[(size_t)(bz*2 + (t>>6))*LQ + qt*64 + (t&63)];
  bf16x8 qf0, qf1;
  {
    const u16* qrow = qk_rowp(qk_r15, qk_ws, bz, qt*64 + wv*16 + n);
    qf0 = *(const bf16x8*)(qrow + gq*8);
    qf1 = *(const bf16x8*)(qrow + 32 + gq*8);
  }
  __syncthreads();
  const float iv0 = INVL[wv*16 + n], iv1 = INVL[64 + wv*16 + n];
  for (int kt = ks*4; kt < ks*4 + 4; kt++){
    #pragma unroll
    for (int jb=0; jb<4; jb++){
      const u16* kr = qk_rowp(qk_r15, qk_ws, bz, kt*64 + jb*16 + n);
      bf16x8 kf0 = *(const bf16x8*)(kr + 64 + gq*8);
      bf16x8 kf1 = *(const bf16x8*)(kr + 96 + gq*8);
      f32x4 e0 = __builtin_amdgcn_mfma_f32_16x16x32_bf16(kf0, qf0, FZ, 0, 0, 0);
      f32x4 e1 = __builtin_amdgcn_mfma_f32_16x16x32_bf16(kf1, qf1, FZ, 0, 0, 0);
      // lane (gq,n) reg r: w[q = wv*16+n][j = jb*16+4gq+r]
      float4 w4;
      w4.x = 0.5f*(__expf(e0[0])*iv0 + __expf(e1[0])*iv1);
      w4.y = 0.5f*(__expf(e0[1])*iv0 + __expf(e1[1])*iv1);
      w4.z = 0.5f*(__expf(e0[2])*iv0 + __expf(e1[2])*iv1);
      w4.w = 0.5f*(__expf(e0[3])*iv0 + __expf(e1[3])*iv1);
      *(float4*)(&STG[(wv*16 + n)*68 + jb*16 + 4*gq]) = w4;
    }
    size_t base = 1 + (size_t)bz*LQ*LQ + (size_t)(qt*64)*LQ + (size_t)kt*64;
    float p = 0.f;
    for (int r=0; r<16; r++){
      int q = wv*16 + r;
      float v = STG[q*68 + lane];
      wout[base + (size_t)q*LQ + lane] = v;
      p += v;
    }
    if (DOIMP) atomicAdd(&imp[bz*LQ + kt*64 + lane], p);
  }
}

// ---------------- top-k (M=8, ties -> lowest index) — LDS serial ----------------
__global__ __launch_bounds__(64) void k_topk(const float* __restrict__ imp,
                                             int* __restrict__ topki){
  __shared__ float v[2048];
  __shared__ float bv[64];
  __shared__ int   bi[64];
  __shared__ int   chosen;
  const int b = blockIdx.x, lane = threadIdx.x;
  for (int i=lane; i<2048; i+=64) v[i] = imp[b*2048 + i];
  __syncthreads();
  for (int m=0; m<8; m++){
    float best = -1e30f; int besti = 1<<30;
    for (int i=lane; i<2048; i+=64)
      if (v[i] > best || (v[i] == best && i < besti)){ best = v[i]; besti = i; }
    bv[lane] = best; bi[lane] = besti;
    __syncthreads();
    if (lane == 0){
      float B = bv[0]; int I = bi[0];
      for (int i2=1; i2<64; i2++)
        if (bv[i2] > B || (bv[i2] == B && bi[i2] < I)){ B = bv[i2]; I = bi[i2]; }
      topki[b*8 + m] = (I < 0) ? 0 : (I > 2047 ? 2047 : I);
      chosen = (I < 0) ? 0 : (I > 2047 ? 2047 : I);
    }
    __syncthreads();
    if (lane == 0) v[chosen] = -1e30f;
    __syncthreads();
  }
}

// ---------------- memory reader + loss — one block per batch, wave-parallel ----
__global__ __launch_bounds__(64) void k_loss(const u16* __restrict__ h,
    const int* __restrict__ topki, const int* __restrict__ query, const int* __restrict__ target,
    const float* __restrict__ qemb, const float* __restrict__ rq_w, const float* __restrict__ rq_b,
    const float* __restrict__ ro_w, const float* __restrict__ ro_b, float* __restrict__ loss_out){
  const int b = blockIdx.x, lane = threadIdx.x;
  float mv[8];
  #pragma unroll
  for (int m=0; m<8; m++){
    int idx = topki[b*8+m] & 2047;
    mv[m] = bfu2f(h[(size_t)(b*LQ + idx)*64 + lane]);
  }
  float qh = qemb[((query[b]&63)<<6) + lane];
  float qd = rq_b[lane];
  for (int k=0;k<64;k++) qd += __shfl(qh,k) * rq_w[lane*64 + k];
  float sc[8];
  #pragma unroll
  for (int m=0;m<8;m++){
    float p = qd * mv[m];
    #pragma unroll
    for (int o=32;o;o>>=1) p += __shfl_xor(p,o);
    sc[m] = p * 0.125f;   // 1/sqrt(64)
  }
  float mx = sc[0];
  #pragma unroll
  for (int m=1;m<8;m++) mx = fmaxf(mx, sc[m]);
  float den = 0.f, rd = 0.f;
  #pragma unroll
  for (int m=0;m<8;m++){ float w = __expf(sc[m]-mx); den += w; rd += w*mv[m]; }
  rd /= den;
  float lg = ro_b[lane];
  for (int d=0;d<64;d++) lg += __shfl(rd,d) * ro_w[lane*64 + d];
  float lmx = lg;
  #pragma unroll
  for (int o=32;o;o>>=1) lmx = fmaxf(lmx, __shfl_xor(lmx,o));
  float ex = __expf(lg - lmx), es = ex;
  #pragma unroll
  for (int o=32;o;o>>=1) es += __shfl_xor(es,o);
  float lt = __shfl(lg, target[b]&63);
  if (lane == 0) atomicAdd(loss_out, -(lt - lmx - logf(es)) * (1.f/16.f));
}

// ---------------- final: f32 loss -> out_f[0] (runs LAST) ----------------
__global__ void k_store_loss(const float* __restrict__ ls, float* __restrict__ out){
  out[0] = ls[0];
}

// ---------------- launch ----------------
extern "C" void kernel_launch(void* const* d_in, const int* in_sizes, int n_in,
                              void* d_out, int out_size, void* d_ws, size_t ws_size,
                              hipStream_t stream){
  const int*   seq    = (const int*)  d_in[0];
  const int*   query  = (const int*)  d_in[1];
  const int*   target = (const int*)  d_in[2];
  const float* embed  = (const float*)d_in[3];
  const float* a1_wi  = (const float*)d_in[4];
  const float* a1_bi  = (const float*)d_in[5];
  const float* a1_wo  = (const float*)d_in[6];
  const float* a1_bo  = (const float*)d_in[7];
  const float* ff1_w1 = (const float*)d_in[8];
  const float* ff1_b1 = (const float*)d_in[9];
  const float* ff1_w2 = (const float*)d_in[10];
  const float* ff1_b2 = (const float*)d_in[11];
  const float* ln1a_g = (const float*)d_in[12];
  const float* ln1a_b = (const float*)d_in[13];
  const float* ln1b_g = (const float*)d_in[14];
  const float* ln1b_b = (const float*)d_in[15];
  const float* a2_wi  = (const float*)d_in[16];
  const float* a2_bi  = (const float*)d_in[17];
  const float* a2_wo  = (const float*)d_in[18];
  const float* a2_bo  = (const float*)d_in[19];
  const float* ff2_w1 = (const float*)d_in[20];
  const float* ff2_b1 = (const float*)d_in[21];
  const float* ff2_w2 = (const float*)d_in[22];
  const float* ff2_b2 = (const float*)d_in[23];
  const float* ln2a_g = (const float*)d_in[24];
  const float* ln2a_b = (const float*)d_in[25];
  const float* ln2b_g = (const float*)d_in[26];
  const float* ln2b_b = (const float*)d_in[27];
  const float* rq_w   = (const float*)d_in[28];
  const float* rq_b   = (const float*)d_in[29];
  const float* ro_w   = (const float*)d_in[30];
  const float* ro_b   = (const float*)d_in[31];
  const float* qemb   = (const float*)d_in[32];

  // d_ws (918,020 B)
  char* wsb      = (char*)d_ws;
  u16*  qk_ws    = (u16*)(wsb);                // 524,288 B (batch 15 [Qs|K])
  float* ws_imp  = (float*)(wsb + 524288);     // 131,072 B
  float* ws_l    = (float*)(wsb + 655360);     // 262,144 B
  int*  ws_top   = (int*)(wsb + 917504);       // 512 B
  float* ws_loss = (float*)(wsb + 918016);     // 4 B

  // d_out (FLOAT32, 268,435,460 B) + scratch parking
  float* out_f  = (float*)d_out;
  u16* qk1     = (u16*)((char*)d_out + 4194368);     // 8 MB layer-1 [Qs|K]
  u16* vg1     = (u16*)((char*)d_out + 12582976);    // 4 MB layer-1 V (j-tiled)
  u16* vg2     = (u16*)((char*)d_out + 4194368);     // 4 MB layer-2 V (j-tiled)
  u16* qk_r15  = (u16*)((char*)d_out + 251658304);   // 7.5 MB, region-15 head
  u16* h16     = (u16*)((char*)d_out + 259522624);   // 4 MB, region-15 tail

  k_embed<<<8192,256,0,stream>>>(seq, embed, h16);
  k_zero<<<128,256,0,stream>>>(ws_imp, ws_loss);
  // layer 1
  k_qkv<0><<<2048,256,0,stream>>>(h16, a1_wi, a1_bi, qk1, nullptr, nullptr, vg1);
  k_attn_ln<0><<<2048,256,0,stream>>>(qk1, nullptr, vg1,
                                      a1_wo, a1_bo, ln1a_g, ln1a_b, h16, nullptr);
  k_ffn<<<512,256,0,stream>>>(h16, ff1_w1, ff1_b1, ff1_w2, ff1_b2, ln1b_g, ln1b_b);
  // layer 2
  k_qkv<1><<<2048,256,0,stream>>>(h16, a2_wi, a2_bi, nullptr, qk_r15, qk_ws, vg2);
  k_attn_ln<1><<<2048,256,0,stream>>>(qk_r15, qk_ws, vg2,
                                      a2_wo, a2_bo, ln2a_g, ln2a_b, h16, ws_l);
  k_ffn<<<512,256,0,stream>>>(h16, ff2_w1, ff2_b1, ff2_w2, ff2_b2, ln2b_g, ln2b_b);
  // attn_w bz0-14 with fused importance (destroys regions 0-14; h16 safe in
  // region-15 tail); then bz15 importance (reads d_ws only)
  k_pass2<1><<<dim3(256,15),256,0,stream>>>(qk_r15, qk_ws, ws_l, ws_imp, out_f, 0);
  k_imp<<<dim3(32,1),256,0,stream>>>(qk_r15, qk_ws, ws_l, ws_imp, 15);
  // topk -> loss (h16 still alive)
  k_topk<<<16,64,0,stream>>>(ws_imp, ws_top);
  k_loss<<<16,64,0,stream>>>(h16, ws_top, query, target, qemb, rq_w, rq_b, ro_w, ro_b, ws_loss);
  // attn_w bz15 (overwrites region 15: qk_r15 + h16 now dead)
  k_pass2<0><<<dim3(256,1),256,0,stream>>>(qk_r15, qk_ws, ws_l, nullptr, out_f, 15);
  // loss stored LAST
  k_store_loss<<<1,1,0,stream>>>(ws_loss, out_f);
}

// Round 5
// 838.113 us; speedup vs baseline: 3.5296x; 1.0291x over previous
//
#include <hip/hip_runtime.h>
#include <hip/hip_bf16.h>

// RecallModel: B=16, L=2048, H=64, NH=2, HD=32, M=8, V=64.
// Inputs: ints int32; floats FP32. OUTPUTS FLOAT32 (reference dtype!):
//   out_f[0] = loss, out_f[1..1+16*2048*2048) = attn_w (B,L,L). 268,435,460 B.
//
// d_ws usage:
//   qk15 @0       524,288 B  bf16 [Qs|K] batch 15 (layer 2)
//   imp  @524288  131,072 B  f32 imp[16][2048]
//   l2   @655360  262,144 B  f32 sum-of-exp
// d_out doubles as scratch (dead-before-overwrite). attn batch-b region =
// bytes [4 + b*16777216, 4 + (b+1)*16777216).
//   qk1    @ byte 4194368    8 MB bf16 layer-1 [Qs|K] rows s128 (dies at attn1)
//   vg1    @ byte 12582976   4 MB bf16 layer-1 V, j-tiled (dies at attn1)
//   vg2    @ byte 4194368    4 MB bf16 layer-2 V, j-tiled (dies at attn2)
//   qk0-14 @ byte 251658304  7.5 MB (region-15 head; dies at pass2 wave2)
//   h      @ byte 259522624  4 MB bf16 (region-15 TAIL; survives pass2 wave1;
//                                 dies at pass2 wave2)
// ORDER: pass2 wave1 (bz0-14, fused importance) -> k_imp15 (8-way split) ->
// k_select (topk+loss -> out_f[0]) -> pass2 wave2 (bz15 overwrites region 15).
//
// V j-tiled layout (per batch): element (j,d) at
//   ((( (j>>5)*4 + ((j>>2)&3) )*64 + d)*8 + ((j>>4)&1)*4 + (j&3)

typedef unsigned short u16;
#define LQ 2048
#define BBATCH 16
#define QKB 262144   // u16 elements per batch of packed [Qs|K] (2048*128)

typedef __attribute__((ext_vector_type(8))) short bf16x8;
typedef __attribute__((ext_vector_type(4))) float f32x4;

__device__ __forceinline__ float bfu2f(u16 x){ return __uint_as_float(((unsigned)x) << 16); }
__device__ __forceinline__ u16 f2bu(float f){ return __bfloat16_as_ushort(__float2bfloat16(f)); }

// packed f32x2 -> bf16x2 (RNE), lo in [15:0]
__device__ __forceinline__ unsigned cvtpk(float lo, float hi){
  unsigned r;
  asm("v_cvt_pk_bf16_f32 %0, %1, %2" : "=v"(r) : "v"(lo), "v"(hi));
  return r;
}

__device__ __forceinline__ const u16* qk_rowp(const u16* qk_r15, const u16* qk_ws,
                                              int bz, int row){
  const u16* base = (bz < 15) ? (qk_r15 + (size_t)bz*QKB) : qk_ws;
  return base + (size_t)row*128;
}
__device__ __forceinline__ u16* qk_rowp_w(u16* qk_r15, u16* qk_ws, int bz, int row){
  u16* base = (bz < 15) ? (qk_r15 + (size_t)bz*QKB) : qk_ws;
  return base + (size_t)row*128;
}

// ---------------- embed ----------------
__global__ __launch_bounds__(256) void k_embed(const int* __restrict__ seq,
                                               const float* __restrict__ emb,
                                               u16* __restrict__ h){
  int i = blockIdx.x*256 + threadIdx.x;      // 32768*64
  int tok = i >> 6, d = i & 63;
  int v = seq[tok] & 63;
  h[i] = f2bu(emb[(v << 6) + d]);
}

__global__ __launch_bounds__(256) void k_zero(float* __restrict__ p, float* __restrict__ q){
  int i = blockIdx.x*256 + threadIdx.x;
  p[i] = 0.f;
  if (i == 0) q[0] = 0.f;
}

// ---------------- qkv projection ----------------
template<int MODE>
__global__ __launch_bounds__(256) void k_qkv(const u16* __restrict__ X,
                                             const float* __restrict__ W,
                                             const float* __restrict__ bias,
                                             u16* __restrict__ dqk0,
                                             u16* __restrict__ dqk_r15,
                                             u16* __restrict__ dqk_ws,
                                             u16* __restrict__ vg){
  __shared__ float WT[64*193];   // [k][mo]
  __shared__ float bs[192];
  const int t = threadIdx.x;
  for (int e=t; e<192*64; e+=256){ int mo=e>>6, k=e&63; WT[k*193+mo] = W[e]; }
  if (t < 192) bs[t] = bias[t];
  __syncthreads();
  const int wid=t>>6, lane=t&63;
  const int tok0 = (blockIdx.x*4 + wid)*4;
  float x[4];
  #pragma unroll
  for (int c=0;c<4;c++) x[c] = bfu2f(X[(tok0+c)*64 + lane]);
  float acc[4][3];
  #pragma unroll
  for (int c=0;c<4;c++)
    #pragma unroll
    for (int m=0;m<3;m++) acc[c][m] = bs[m*64 + lane];
  for (int k=0;k<64;k++){
    float wv[3];
    #pragma unroll
    for (int m=0;m<3;m++) wv[m] = WT[k*193 + m*64 + lane];
    #pragma unroll
    for (int c=0;c<4;c++){
      float xk = __shfl(x[c], k);
      #pragma unroll
      for (int m=0;m<3;m++) acc[c][m] += xk*wv[m];
    }
  }
  const float qs = 0.17677669529663688f;  // 1/sqrt(32)
  #pragma unroll
  for (int c=0;c<4;c++){
    int tok = tok0+c;
    float vq = acc[c][0]*qs, vk = acc[c][1], vv = acc[c][2];
    int b = tok >> 11, r = tok & 2047;
    u16* row = (MODE==0) ? (dqk0 + (size_t)tok*128) : qk_rowp_w(dqk_r15, dqk_ws, b, r);
    row[lane]      = f2bu(vq);
    row[64 + lane] = f2bu(vk);
    vg[((size_t)((b*64 + (r>>5))*4 + ((r>>2)&3))*64 + lane)*8
       + ((r>>4)&1)*4 + (r&3)] = f2bu(vv);
  }
}

// ---------------- attention v2 (MFMA) + fused proj+residual+LN --------------
// Block = 32 queries (2 q-sets of 16); 4 waves SPLIT THE KEY RANGE (512 keys
// each). K/V fragments loaded ONCE per k-tile, reused by both q-sets (halves
// VMEM bytes/query). exp in f32; P packed via v_cvt_pk_bf16_f32; PV A-frag
// built in-lane. No barriers in the main loop. Partial O / denominators are
// combined via LDS atomicAdd (ds_add_f32), then proj+residual+LN.
// Grid 1024, XCD-bijective remap: XCD x gets batches {2x, 2x+1} (~1.5 MB L2).
template<int MODE>
__global__ __launch_bounds__(256, 4) void k_attn_ln(const u16* __restrict__ PQK,
    const u16* __restrict__ QKWS, const u16* __restrict__ VG,
    const float* __restrict__ wo, const float* __restrict__ bo,
    const float* __restrict__ g, const float* __restrict__ be,
    u16* __restrict__ h, float* __restrict__ lout){
  __shared__ float R[4096];          // phase A: OACC[32][64]; phase B: WOT
  __shared__ float ST[32*68];        // [q][d] normalized attn out (padded)
  __shared__ float DN[2][32];        // denominator accumulators
  __shared__ float CB[192];          // bo | g | be
  const int lin = blockIdx.x;        // 1024 blocks = 8 XCD * 128
  const int nid = (lin & 7)*128 + (lin >> 3);
  const int qt = nid & 63, bz = nid >> 6;
  const int t = threadIdx.x;
  const int lane = t & 63, wv = t >> 6;
  const int n = lane & 15, gq = lane >> 4;
  const f32x4 FZ = {0.f, 0.f, 0.f, 0.f};

  for (int e=t; e<2048; e+=256) R[e] = 0.f;
  if (t < 64) DN[t>>5][t&31] = 0.f;
  __syncthreads();

  // Q fragments: 2 q-sets, rows q = qt*32 + qa*16 + n
  bf16x8 qf[2][2];
  #pragma unroll
  for (int qa=0; qa<2; qa++){
    const u16* qrow = (MODE==0) ? (PQK + (size_t)(bz*LQ + qt*32 + qa*16 + n)*128)
                                : qk_rowp(PQK, QKWS, bz, qt*32 + qa*16 + n);
    qf[qa][0] = *(const bf16x8*)(qrow + gq*8);
    qf[qa][1] = *(const bf16x8*)(qrow + 32 + gq*8);
  }
  f32x4 o[2][2][2];                  // [qa][hh][db]
  #pragma unroll
  for (int qa=0; qa<2; qa++)
    #pragma unroll
    for (int hh=0; hh<2; hh++)
      #pragma unroll
      for (int db=0; db<2; db++) o[qa][hh][db] = FZ;
  float dacc[2][2] = {{0.f,0.f},{0.f,0.f}};

  #pragma unroll 1
  for (int kt=wv*8; kt<wv*8+8; kt++){
    #pragma unroll
    for (int hh=0; hh<2; hh++){
      // K fragments once per tile (shared by both q-sets)
      bf16x8 kf[4];
      #pragma unroll
      for (int jb=0; jb<4; jb++){
        const u16* kr = (MODE==0) ? (PQK + (size_t)(bz*LQ + kt*64 + jb*16 + n)*128)
                                  : qk_rowp(PQK, QKWS, bz, kt*64 + jb*16 + n);
        kf[jb] = *(const bf16x8*)(kr + 64 + hh*32 + gq*8);
      }
      unsigned pk[2][4][2];
      #pragma unroll
      for (int qa=0; qa<2; qa++){
        f32x4 ev[4];
        #pragma unroll
        for (int jb=0; jb<4; jb++)
          ev[jb] = __builtin_amdgcn_mfma_f32_16x16x32_bf16(kf[jb], qf[qa][hh], FZ, 0, 0, 0);
        float ds = 0.f;
        #pragma unroll
        for (int jb=0; jb<4; jb++){
          float e0 = __expf(ev[jb][0]), e1 = __expf(ev[jb][1]);
          float e2 = __expf(ev[jb][2]), e3 = __expf(ev[jb][3]);
          ds += (e0+e1) + (e2+e3);
          pk[qa][jb][0] = cvtpk(e0, e1);
          pk[qa][jb][1] = cvtpk(e2, e3);
        }
        dacc[qa][hh] += ds;
      }
      #pragma unroll
      for (int kb=0; kb<2; kb++){
        union { unsigned u[4]; bf16x8 v; } af[2];
        #pragma unroll
        for (int qa=0; qa<2; qa++){
          af[qa].u[0] = pk[qa][2*kb][0];   af[qa].u[1] = pk[qa][2*kb][1];
          af[qa].u[2] = pk[qa][2*kb+1][0]; af[qa].u[3] = pk[qa][2*kb+1][1];
        }
        #pragma unroll
        for (int db=0; db<2; db++){
          const int d = hh*32 + db*16 + n;
          const bf16x8 vf = *(const bf16x8*)(VG +
              ((size_t)((bz*64 + kt*2 + kb)*4 + gq)*64 + d)*8);
          #pragma unroll
          for (int qa=0; qa<2; qa++)
            o[qa][hh][db] = __builtin_amdgcn_mfma_f32_16x16x32_bf16(af[qa].v, vf, o[qa][hh][db], 0, 0, 0);
        }
      }
    }
  }
  // combine partial denominators (reduce gq via shfl, add across waves in LDS)
  #pragma unroll
  for (int qa=0; qa<2; qa++)
    #pragma unroll
    for (int hh=0; hh<2; hh++){
      float s = dacc[qa][hh];
      s += __shfl_xor(s, 16);
      s += __shfl_xor(s, 32);
      if (gq == 0) atomicAdd(&DN[hh][qa*16 + n], s);
    }
  // combine partial O: lane holds O[q=qa*16+gq*4+r][d=hh*32+db*16+n]
  #pragma unroll
  for (int qa=0; qa<2; qa++)
    #pragma unroll
    for (int hh=0; hh<2; hh++)
      #pragma unroll
      for (int db=0; db<2; db++)
        #pragma unroll
        for (int r=0; r<4; r++)
          atomicAdd(&R[(qa*16 + gq*4 + r)*64 + hh*32 + db*16 + n], o[qa][hh][db][r]);
  __syncthreads();
  if (lout && t < 64)
    lout[(size_t)(bz*2 + (t>>5))*LQ + qt*32 + (t&31)] = DN[t>>5][t&31];
  // normalize -> ST
  for (int e=t; e<2048; e+=256){
    int q = e >> 6, d = e & 63;
    ST[q*68 + d] = R[e] / DN[d>>5][q];
  }
  __syncthreads();                   // OACC dead; reuse R as WOT
  for (int e2=t; e2<4096; e2+=256){ int k=e2>>6, mo=e2&63; R[e2] = wo[mo*64+k]; }
  if (t < 64)       CB[t] = bo[t];
  else if (t < 128) CB[t] = g[t-64];
  else if (t < 192) CB[t] = be[t-128];
  __syncthreads();
  // proj + residual + LN (8 tokens per wave)
  for (int r=0; r<8; r++){
    int tl = wv*8 + r;
    size_t gtok = (size_t)(bz*LQ + qt*32 + tl);
    float acc = CB[lane];
    for (int k=0; k<64; k++) acc += ST[tl*68 + k] * R[k*64 + lane];
    float rr = acc + bfu2f(h[gtok*64 + lane]);
    float s = rr;
    #pragma unroll
    for (int ofs=32; ofs; ofs>>=1) s += __shfl_xor(s, ofs);
    float mean = s * (1.f/64.f);
    float dv = rr - mean;
    float vs = dv*dv;
    #pragma unroll
    for (int ofs=32; ofs; ofs>>=1) vs += __shfl_xor(vs, ofs);
    float rstd = 1.f/sqrtf(vs*(1.f/64.f) + 1e-5f);
    h[gtok*64 + lane] = f2bu(dv*rstd*CB[64+lane] + CB[128+lane]);
  }
}

// ---------------- fused FFN + residual + LN (MFMA) ----------------
__global__ __launch_bounds__(256) void k_ffn(u16* __restrict__ h,
    const float* __restrict__ w1, const float* __restrict__ b1,
    const float* __restrict__ w2, const float* __restrict__ b2,
    const float* __restrict__ g, const float* __restrict__ be){
  __shared__ u16 W1L[128*64];      // [h1row][64 d] swizzled
  __shared__ u16 W2L[64*192];      // [o][6 kblk * 32] swizzled (4 W2 + 2 I)
  __shared__ u16 YL[64*64];        // y bf16 staging (swizzled by row)
  __shared__ float B1[128], B2F[64], G[64], Bb[64];
  const int t = threadIdx.x;
  for (int e=t; e<8192; e+=256){
    int row = e>>6, col = e&63;
    W1L[row*64 + (col ^ ((row&7)<<3))] = f2bu(w1[e]);
  }
  for (int e=t; e<12288; e+=256){
    int o = e/192, rem = e%192, u = rem>>5, gs = rem&31, gq2 = gs>>3, s = gs&7;
    float val;
    if (u < 4) val = w2[o*128 + u*32 + ((s>>2)<<4) + gq2*4 + (s&3)];
    else { int d = ((u-4)<<5) + gq2*8 + s; val = (d==o) ? 1.f : 0.f; }
    W2L[o*192 + ((u*32+gs) ^ ((o&7)<<3))] = f2bu(val);
  }
  if (t < 128) B1[t] = b1[t];
  if (t < 64){ B2F[t] = b2[t]; G[t] = g[t]; Bb[t] = be[t]; }
  __syncthreads();
  const int lane = t & 63, wv = t >> 6;
  const int n = lane & 15, gq = lane >> 4;
  const int tok0 = blockIdx.x*64 + wv*16;
  bf16x8 xf[2];
  xf[0] = *(const bf16x8*)(h + (size_t)(tok0+n)*64 + gq*8);
  xf[1] = *(const bf16x8*)(h + (size_t)(tok0+n)*64 + 32 + gq*8);
  f32x4 acc1[8];
  #pragma unroll
  for (int ct=0; ct<8; ct++){
    f32x4 c;
    #pragma unroll
    for (int r=0;r<4;r++) c[r] = B1[ct*16 + gq*4 + r];
    bf16x8 w1f0 = *(const bf16x8*)(W1L + (ct*16+n)*64 + ((gq*8) ^ ((n&7)<<3)));
    bf16x8 w1f1 = *(const bf16x8*)(W1L + (ct*16+n)*64 + ((32+gq*8) ^ ((n&7)<<3)));
    c = __builtin_amdgcn_mfma_f32_16x16x32_bf16(w1f0, xf[0], c, 0, 0, 0);
    c = __builtin_amdgcn_mfma_f32_16x16x32_bf16(w1f1, xf[1], c, 0, 0, 0);
    acc1[ct] = c;
  }
  f32x4 acc2[4];
  #pragma unroll
  for (int ot=0; ot<4; ot++)
    #pragma unroll
    for (int r=0;r<4;r++) acc2[ot][r] = B2F[ot*16 + gq*4 + r];
  #pragma unroll
  for (int u=0; u<6; u++){
    union { unsigned uu[4]; bf16x8 v; } bfr;
    if (u < 4){
      #pragma unroll
      for (int i=0;i<4;i++){
        int ct = u*2 + (i>>1);
        float a = fmaxf(acc1[ct][(2*i)&3], 0.f);
        float b = fmaxf(acc1[ct][(2*i+1)&3], 0.f);
        bfr.uu[i] = (unsigned)f2bu(a) | ((unsigned)f2bu(b) << 16);
      }
    } else {
      bfr.v = xf[u-4];
    }
    #pragma unroll
    for (int ot=0; ot<4; ot++){
      bf16x8 w2f = *(const bf16x8*)(W2L + (ot*16+n)*192 + ((u*32+gq*8) ^ ((n&7)<<3)));
      acc2[ot] = __builtin_amdgcn_mfma_f32_16x16x32_bf16(w2f, bfr.v, acc2[ot], 0, 0, 0);
    }
  }
  float s1 = 0.f;
  #pragma unroll
  for (int ot=0;ot<4;ot++)
    #pragma unroll
    for (int r=0;r<4;r++) s1 += acc2[ot][r];
  s1 += __shfl_xor(s1, 16); s1 += __shfl_xor(s1, 32);
  float mean = s1 * (1.f/64.f);
  float s2 = 0.f;
  #pragma unroll
  for (int ot=0;ot<4;ot++)
    #pragma unroll
    for (int r=0;r<4;r++){ float dv = acc2[ot][r]-mean; s2 += dv*dv; }
  s2 += __shfl_xor(s2, 16); s2 += __shfl_xor(s2, 32);
  float rstd = 1.f/sqrtf(s2*(1.f/64.f) + 1e-5f);
  #pragma unroll
  for (int ot=0;ot<4;ot++)
    #pragma unroll
    for (int r=0;r<4;r++){
      int o = ot*16 + gq*4 + r;
      float yv = (acc2[ot][r]-mean)*rstd*G[o] + Bb[o];
      YL[(wv*16+n)*64 + (o ^ ((n&7)<<3))] = f2bu(yv);
    }
  __syncthreads();
  unsigned* h32 = (unsigned*)(h + (size_t)(blockIdx.x)*64*64);
  #pragma unroll
  for (int i=0;i<8;i++){
    int idx = i*64 + lane;
    int row = wv*16 + (idx>>5), c32 = idx&31;
    unsigned vv = *(const unsigned*)(YL + row*64 + ((c32*2) ^ ((row&7)<<3)));
    h32[row*32 + c32] = vv;
  }
}

// ---------------- importance (MFMA), k-range split, one batch ----------------
// Grid 256: blockIdx.x = qt*8 + ks; kt in [ks*4, ks*4+4). Used for bz=15 only.
__global__ __launch_bounds__(256) void k_imp(const u16* __restrict__ qk_r15,
    const u16* __restrict__ qk_ws, const float* __restrict__ l2,
    float* __restrict__ imp, int bz0){
  __shared__ float IMPS[256];
  __shared__ float INVL[128];
  const int t = threadIdx.x;
  const int qt = blockIdx.x >> 3, ks = blockIdx.x & 7;
  const int bz = bz0;
  const int lane = t & 63, wv = t >> 6;
  const int n = lane & 15, gq = lane >> 4;
  const f32x4 FZ = {0.f, 0.f, 0.f, 0.f};
  if (t < 128) INVL[t] = 1.f / l2[(size_t)(bz*2 + (t>>6))*LQ + qt*64 + (t&63)];
  IMPS[t] = 0.f;
  bf16x8 qf0, qf1;
  {
    const u16* qrow = qk_rowp(qk_r15, qk_ws, bz, qt*64 + wv*16 + n);
    qf0 = *(const bf16x8*)(qrow + gq*8);
    qf1 = *(const bf16x8*)(qrow + 32 + gq*8);
  }
  __syncthreads();
  float iv0[4], iv1[4];
  #pragma unroll
  for (int r=0;r<4;r++){
    iv0[r] = INVL[wv*16 + gq*4 + r];
    iv1[r] = INVL[64 + wv*16 + gq*4 + r];
  }
  for (int kt=ks*4; kt<ks*4+4; kt++){
    #pragma unroll
    for (int jb=0; jb<4; jb++){
      const u16* kr = qk_rowp(qk_r15, qk_ws, bz, kt*64 + jb*16 + n);
      bf16x8 kf0 = *(const bf16x8*)(kr + 64 + gq*8);
      bf16x8 kf1 = *(const bf16x8*)(kr + 96 + gq*8);
      f32x4 e0 = __builtin_amdgcn_mfma_f32_16x16x32_bf16(qf0, kf0, FZ, 0, 0, 0);
      f32x4 e1 = __builtin_amdgcn_mfma_f32_16x16x32_bf16(qf1, kf1, FZ, 0, 0, 0);
      float cs = 0.f;
      #pragma unroll
      for (int r=0;r<4;r++)
        cs += 0.5f*(__expf(e0[r])*iv0[r] + __expf(e1[r])*iv1[r]);
      cs += __shfl_xor(cs, 16);
      cs += __shfl_xor(cs, 32);
      if (gq == 0) atomicAdd(&IMPS[(kt-ks*4)*64 + jb*16 + n], cs);
    }
  }
  __syncthreads();
  atomicAdd(&imp[bz*LQ + ks*256 + t], IMPS[t]);
}

// ---------------- pass2 (MFMA): scores -> attn_w FLOAT32 (+fused importance) -
// 1-D grid, XCD remap with nper blocks/XCD: nid=(x&7)*nper+(x>>3);
// bz = bz0 + nid>>8; rem=nid&255; qt=rem>>3, ks=rem&7; kt in [ks*4, ks*4+4).
template<int DOIMP>
__global__ __launch_bounds__(256) void k_pass2(const u16* __restrict__ qk_r15,
    const u16* __restrict__ qk_ws, const float* __restrict__ l2,
    float* __restrict__ imp, float* __restrict__ wout, int bz0, int nper){
  __shared__ float STG[64*68];       // [q][j] staging, per-wave-private rows
  __shared__ float INVL[128];
  const int x = blockIdx.x;
  const int nid = (x & 7)*nper + (x >> 3);
  const int bz = bz0 + (nid >> 8);
  const int rem = nid & 255;
  const int qt = rem >> 3, ks = rem & 7;
  const int t = threadIdx.x;
  const int lane = t & 63, wv = t >> 6;
  const int n = lane & 15, gq = lane >> 4;
  const f32x4 FZ = {0.f, 0.f, 0.f, 0.f};
  if (t < 128) INVL[t] = 1.f / l2[(size_t)(bz*2 + (t>>6))*LQ + qt*64 + (t&63)];
  bf16x8 qf0, qf1;
  {
    const u16* qrow = qk_rowp(qk_r15, qk_ws, bz, qt*64 + wv*16 + n);
    qf0 = *(const bf16x8*)(qrow + gq*8);
    qf1 = *(const bf16x8*)(qrow + 32 + gq*8);
  }
  __syncthreads();
  const float iv0 = INVL[wv*16 + n], iv1 = INVL[64 + wv*16 + n];
  for (int kt = ks*4; kt < ks*4 + 4; kt++){
    #pragma unroll
    for (int jb=0; jb<4; jb++){
      const u16* kr = qk_rowp(qk_r15, qk_ws, bz, kt*64 + jb*16 + n);
      bf16x8 kf0 = *(const bf16x8*)(kr + 64 + gq*8);
      bf16x8 kf1 = *(const bf16x8*)(kr + 96 + gq*8);
      f32x4 e0 = __builtin_amdgcn_mfma_f32_16x16x32_bf16(kf0, qf0, FZ, 0, 0, 0);
      f32x4 e1 = __builtin_amdgcn_mfma_f32_16x16x32_bf16(kf1, qf1, FZ, 0, 0, 0);
      float4 w4;
      w4.x = 0.5f*(__expf(e0[0])*iv0 + __expf(e1[0])*iv1);
      w4.y = 0.5f*(__expf(e0[1])*iv0 + __expf(e1[1])*iv1);
      w4.z = 0.5f*(__expf(e0[2])*iv0 + __expf(e1[2])*iv1);
      w4.w = 0.5f*(__expf(e0[3])*iv0 + __expf(e1[3])*iv1);
      *(float4*)(&STG[(wv*16 + n)*68 + jb*16 + 4*gq]) = w4;
    }
    size_t base = 1 + (size_t)bz*LQ*LQ + (size_t)(qt*64)*LQ + (size_t)kt*64;
    float p = 0.f;
    for (int r=0; r<16; r++){
      int q = wv*16 + r;
      float v = STG[q*68 + lane];
      wout[base + (size_t)q*LQ + lane] = v;
      p += v;
    }
    if (DOIMP) atomicAdd(&imp[bz*LQ + kt*64 + lane], p);
  }
}

// ---------------- top-k + memory reader + loss (merged, per batch) ----------
__global__ __launch_bounds__(64) void k_select(const float* __restrict__ imp,
    const u16* __restrict__ h,
    const int* __restrict__ query, const int* __restrict__ target,
    const float* __restrict__ qemb, const float* __restrict__ rq_w, const float* __restrict__ rq_b,
    const float* __restrict__ ro_w, const float* __restrict__ ro_b, float* __restrict__ out0){
  __shared__ float v[2048];
  __shared__ float bv[64];
  __shared__ int   bi[64];
  __shared__ int   chosen;
  __shared__ int   topi[8];
  const int b = blockIdx.x, lane = threadIdx.x;
  for (int i=lane; i<2048; i+=64) v[i] = imp[b*2048 + i];
  __syncthreads();
  for (int m=0; m<8; m++){
    float best = -1e30f; int besti = 1<<30;
    for (int i=lane; i<2048; i+=64)
      if (v[i] > best || (v[i] == best && i < besti)){ best = v[i]; besti = i; }
    bv[lane] = best; bi[lane] = besti;
    __syncthreads();
    if (lane == 0){
      float B = bv[0]; int I = bi[0];
      for (int i2=1; i2<64; i2++)
        if (bv[i2] > B || (bv[i2] == B && bi[i2] < I)){ B = bv[i2]; I = bi[i2]; }
      int c = (I < 0) ? 0 : (I > 2047 ? 2047 : I);
      topi[m] = c;
      chosen = c;
    }
    __syncthreads();
    if (lane == 0) v[chosen] = -1e30f;
    __syncthreads();
  }
  float mv[8];
  #pragma unroll
  for (int m=0; m<8; m++){
    int idx = topi[m] & 2047;
    mv[m] = bfu2f(h[(size_t)(b*LQ + idx)*64 + lane]);
  }
  float qh = qemb[((query[b]&63)<<6) + lane];
  float qd = rq_b[lane];
  for (int k=0;k<64;k++) qd += __shfl(qh,k) * rq_w[lane*64 + k];
  float sc[8];
  #pragma unroll
  for (int m=0;m<8;m++){
    float p = qd * mv[m];
    #pragma unroll
    for (int o=32;o;o>>=1) p += __shfl_xor(p,o);
    sc[m] = p * 0.125f;   // 1/sqrt(64)
  }
  float mx = sc[0];
  #pragma unroll
  for (int m=1;m<8;m++) mx = fmaxf(mx, sc[m]);
  float den = 0.f, rd = 0.f;
  #pragma unroll
  for (int m=0;m<8;m++){ float w = __expf(sc[m]-mx); den += w; rd += w*mv[m]; }
  rd /= den;
  float lg = ro_b[lane];
  for (int d=0;d<64;d++) lg += __shfl(rd,d) * ro_w[lane*64 + d];
  float lmx = lg;
  #pragma unroll
  for (int o=32;o;o>>=1) lmx = fmaxf(lmx, __shfl_xor(lmx,o));
  float ex = __expf(lg - lmx), es = ex;
  #pragma unroll
  for (int o=32;o;o>>=1) es += __shfl_xor(es,o);
  float lt = __shfl(lg, target[b]&63);
  if (lane == 0) atomicAdd(out0, -(lt - lmx - logf(es)) * (1.f/16.f));
}

// ---------------- launch ----------------
extern "C" void kernel_launch(void* const* d_in, const int* in_sizes, int n_in,
                              void* d_out, int out_size, void* d_ws, size_t ws_size,
                              hipStream_t stream){
  const int*   seq    = (const int*)  d_in[0];
  const int*   query  = (const int*)  d_in[1];
  const int*   target = (const int*)  d_in[2];
  const float* embed  = (const float*)d_in[3];
  const float* a1_wi  = (const float*)d_in[4];
  const float* a1_bi  = (const float*)d_in[5];
  const float* a1_wo  = (const float*)d_in[6];
  const float* a1_bo  = (const float*)d_in[7];
  const float* ff1_w1 = (const float*)d_in[8];
  const float* ff1_b1 = (const float*)d_in[9];
  const float* ff1_w2 = (const float*)d_in[10];
  const float* ff1_b2 = (const float*)d_in[11];
  const float* ln1a_g = (const float*)d_in[12];
  const float* ln1a_b = (const float*)d_in[13];
  const float* ln1b_g = (const float*)d_in[14];
  const float* ln1b_b = (const float*)d_in[15];
  const float* a2_wi  = (const float*)d_in[16];
  const float* a2_bi  = (const float*)d_in[17];
  const float* a2_wo  = (const float*)d_in[18];
  const float* a2_bo  = (const float*)d_in[19];
  const float* ff2_w1 = (const float*)d_in[20];
  const float* ff2_b1 = (const float*)d_in[21];
  const float* ff2_w2 = (const float*)d_in[22];
  const float* ff2_b2 = (const float*)d_in[23];
  const float* ln2a_g = (const float*)d_in[24];
  const float* ln2a_b = (const float*)d_in[25];
  const float* ln2b_g = (const float*)d_in[26];
  const float* ln2b_b = (const float*)d_in[27];
  const float* rq_w   = (const float*)d_in[28];
  const float* rq_b   = (const float*)d_in[29];
  const float* ro_w   = (const float*)d_in[30];
  const float* ro_b   = (const float*)d_in[31];
  const float* qemb   = (const float*)d_in[32];

  // d_ws
  char* wsb      = (char*)d_ws;
  u16*  qk_ws    = (u16*)(wsb);                // 524,288 B (batch 15 [Qs|K])
  float* ws_imp  = (float*)(wsb + 524288);     // 131,072 B
  float* ws_l    = (float*)(wsb + 655360);     // 262,144 B

  // d_out (FLOAT32, 268,435,460 B) + scratch parking
  float* out_f  = (float*)d_out;
  u16* qk1     = (u16*)((char*)d_out + 4194368);     // 8 MB layer-1 [Qs|K]
  u16* vg1     = (u16*)((char*)d_out + 12582976);    // 4 MB layer-1 V (j-tiled)
  u16* vg2     = (u16*)((char*)d_out + 4194368);     // 4 MB layer-2 V (j-tiled)
  u16* qk_r15  = (u16*)((char*)d_out + 251658304);   // 7.5 MB, region-15 head
  u16* h16     = (u16*)((char*)d_out + 259522624);   // 4 MB, region-15 tail

  k_embed<<<8192,256,0,stream>>>(seq, embed, h16);
  k_zero<<<128,256,0,stream>>>(ws_imp, out_f);
  // layer 1
  k_qkv<0><<<2048,256,0,stream>>>(h16, a1_wi, a1_bi, qk1, nullptr, nullptr, vg1);
  k_attn_ln<0><<<1024,256,0,stream>>>(qk1, nullptr, vg1,
                                      a1_wo, a1_bo, ln1a_g, ln1a_b, h16, nullptr);
  k_ffn<<<512,256,0,stream>>>(h16, ff1_w1, ff1_b1, ff1_w2, ff1_b2, ln1b_g, ln1b_b);
  // layer 2
  k_qkv<1><<<2048,256,0,stream>>>(h16, a2_wi, a2_bi, nullptr, qk_r15, qk_ws, vg2);
  k_attn_ln<1><<<1024,256,0,stream>>>(qk_r15, qk_ws, vg2,
                                      a2_wo, a2_bo, ln2a_g, ln2a_b, h16, ws_l);
  k_ffn<<<512,256,0,stream>>>(h16, ff2_w1, ff2_b1, ff2_w2, ff2_b2, ln2b_g, ln2b_b);
  // attn_w bz0-14 with fused importance (destroys regions 0-14; h16 safe in
  // region-15 tail); then bz15 importance (reads d_ws only, 8-way k-split)
  k_pass2<1><<<3840,256,0,stream>>>(qk_r15, qk_ws, ws_l, ws_imp, out_f, 0, 480);
  k_imp<<<256,256,0,stream>>>(qk_r15, qk_ws, ws_l, ws_imp, 15);
  // topk + loss (h16 still alive); loss -> out_f[0] (never touched again)
  k_select<<<16,64,0,stream>>>(ws_imp, h16, query, target, qemb,
                               rq_w, rq_b, ro_w, ro_b, out_f);
  // attn_w bz15 (overwrites region 15: qk_r15 + h16 now dead)
  k_pass2<0><<<256,256,0,stream>>>(qk_r15, qk_ws, ws_l, nullptr, out_f, 15, 32);
}